// Round 12
// baseline (2484.889 us; speedup 1.0000x reference)
//
#include <hip/hip_runtime.h>
#include <stdint.h>

// ---------------------------------------------------------------------------
// Edgewise (eSCN SO(2) conv block), MI355X gfx950.
// Round 12: glue kernels vectorized (G13): k_gate all-u16x8; k_recomb2 stages
// inputs via u16x8 into LDS. GEMM core = round-9 2-phase (751 TF plateau).
// dst-sorted run-gather wig_inv with plain stores for contained runs.
// ---------------------------------------------------------------------------

#define E_NUM   20000
#define NN      5000

typedef uint16_t u16;
typedef __bf16  bf16x8 __attribute__((ext_vector_type(8)));
typedef float   f32x4  __attribute__((ext_vector_type(4)));
typedef uint16_t u16x8 __attribute__((ext_vector_type(8)));

__device__ __forceinline__ float bf2f(u16 h){
  uint32_t u = ((uint32_t)h) << 16;
  return __builtin_bit_cast(float, u);
}
__device__ __forceinline__ u16 f2bf(float f){
  uint32_t u = __builtin_bit_cast(uint32_t, f);
  u += 0x7fffu + ((u >> 16) & 1u);
  return (u16)(u >> 16);
}
__device__ __forceinline__ float sigm(float x){ return 1.f / (1.f + __expf(-x)); }

__device__ __forceinline__ void gload16(const void* g, void* l){
  __builtin_amdgcn_global_load_lds(
      (const __attribute__((address_space(1))) void*)g,
      (__attribute__((address_space(3))) void*)l, 16, 0, 0);
}

// bijective XCD swizzle (m204): contiguous wgid ranges per XCD
__device__ __forceinline__ int swz8(int orig, int nwg){
  int q = nwg >> 3, r = nwg & 7;
  int x = orig & 7, p = orig >> 3;
  int base = (x < r) ? x * (q + 1) : r * (q + 1) + (x - r) * q;
  return base + p;
}

// ----------------------- dst counting sort ---------------------------------
__global__ void k_hist(const int* __restrict__ eidx, int* __restrict__ cnt){
  int e = blockIdx.x * 256 + threadIdx.x;
  if (e < E_NUM) atomicAdd(&cnt[eidx[E_NUM + e]], 1);
}
__global__ __launch_bounds__(256) void k_scan(const int* __restrict__ cnt,
                                              int* __restrict__ off){
  __shared__ int part[256];
  int t = threadIdx.x;
  int s = 0;
  #pragma unroll
  for (int i = 0; i < 20; ++i){
    int idx = t * 20 + i;
    if (idx < NN) s += cnt[idx];
  }
  part[t] = s;
  __syncthreads();
  if (t == 0){
    int run = 0;
    for (int i = 0; i < 256; ++i){ int v = part[i]; part[i] = run; run += v; }
  }
  __syncthreads();
  int run = part[t];
  #pragma unroll
  for (int i = 0; i < 20; ++i){
    int idx = t * 20 + i;
    if (idx < NN){ off[idx] = run; run += cnt[idx]; }
  }
}
__global__ void k_scatter(const int* __restrict__ eidx, int* __restrict__ off,
                          int* __restrict__ perm){
  int e = blockIdx.x * 256 + threadIdx.x;
  if (e < E_NUM){
    int pos = atomicAdd(&off[eidx[E_NUM + e]], 1);
    perm[pos] = e;
  }
}

// --------------------------- weight transpose ------------------------------
__global__ void k_transpose_w(const float* __restrict__ in, u16* __restrict__ out,
                              int K, int N){
  __shared__ float t[32][33];
  int nb = blockIdx.x * 32, kb = blockIdx.y * 32;
  int tx = threadIdx.x & 31, ty = threadIdx.x >> 5;   // 32x8
  for (int i = ty; i < 32; i += 8)
    t[i][tx] = in[(size_t)(kb + i) * N + (nb + tx)];
  __syncthreads();
  for (int i = ty; i < 32; i += 8)
    out[(size_t)(nb + i) * K + (kb + tx)] = f2bf(t[tx][i]);
}

// ------------- x -> xT bf16, [node][c=128][k=64 padded], once --------------
__global__ __launch_bounds__(256) void k_xpose(const float* __restrict__ x,
                                               u16* __restrict__ xT){
  __shared__ float t[6272];
  int n = blockIdx.x, tid = threadIdx.x;
  const float* xp = x + (size_t)n * 6272;
  for (int i = tid; i < 6272; i += 256) t[i] = xp[i];
  __syncthreads();
  int c = tid >> 1;
  int kh = (tid & 1) * 32;
  u16* o = xT + (size_t)n * 8192 + c * 64 + kh;
  #pragma unroll
  for (int q = 0; q < 4; ++q){
    u16x8 h;
    #pragma unroll
    for (int i = 0; i < 8; ++i){
      int k = kh + q * 8 + i;
      h[i] = (k < 49) ? f2bf(t[k * 128 + c]) : (u16)0;
    }
    *(u16x8*)(o + q * 8) = h;
  }
}

// gather x_edge rows in permuted order -> bf16
__global__ void k_gather_xe(const float* __restrict__ x_edge,
                            const int* __restrict__ perm,
                            u16* __restrict__ xe, int e0){
  int el = blockIdx.x, c = threadIdx.x;
  int pe = perm[e0 + el];
  xe[(size_t)el * 128 + c] = f2bf(x_edge[(size_t)pe * 128 + c]);
}

// ---------------------- GEMM core (round-9 structure) ----------------------
struct Seg {
  const u16* A; const u16* B; u16* C; const float* bias;
  int M, N, K, lda, blk0;
};
struct Seg5 { Seg s[5]; int nwg; };

__device__ __forceinline__ void gemm_tile(
    const u16* __restrict__ A, int lda, const u16* __restrict__ B,
    const float* __restrict__ bias, float* __restrict__ Cf,
    u16* __restrict__ Cb, int ldc, int M, int N, int K,
    int bm, int bn, u16* As /*2*4096*/, u16* Bs /*2*4096*/)
{
  const int tid  = threadIdx.x;
  const int lane = tid & 63;
  const int wave = tid >> 6;
  const int wm = wave >> 1, wn = wave & 1;
  const int fr = lane & 15, fq = lane >> 4;
  const int row0 = bm * 128;

  const int lr  = lane >> 2;
  const int lg  = lane & 3;
  const int rA0 = wave * 32 + lr;
  const int rA1 = rA0 + 16;
  const int g0  = lg ^ ((rA0 >> 1) & 3);
  const int g1  = lg ^ ((rA1 >> 1) & 3);
  int gra0 = row0 + rA0; if (gra0 > M - 1) gra0 = M - 1;
  int gra1 = row0 + rA1; if (gra1 > M - 1) gra1 = M - 1;
  const u16* aS0 = A + (size_t)gra0 * lda + g0 * 8;
  const u16* aS1 = A + (size_t)gra1 * lda + g1 * 8;
  const u16* bS0 = B + (size_t)(bn * 128 + rA0) * K + g0 * 8;
  const u16* bS1 = B + (size_t)(bn * 128 + rA1) * K + g1 * 8;
  const int dA0 = (wave * 32) * 32;
  const int dA1 = (wave * 32 + 16) * 32;

  int aoff[4], boff[4];
  #pragma unroll
  for (int mi = 0; mi < 4; ++mi){
    int r = wm * 64 + mi * 16 + fr;
    aoff[mi] = r * 32 + (fq ^ ((r >> 1) & 3)) * 8;
  }
  #pragma unroll
  for (int ni = 0; ni < 4; ++ni){
    int r = wn * 64 + ni * 16 + fr;
    boff[ni] = r * 32 + (fq ^ ((r >> 1) & 3)) * 8;
  }

  f32x4 acc[4][4];
  #pragma unroll
  for (int i = 0; i < 4; ++i)
    #pragma unroll
    for (int j = 0; j < 4; ++j) acc[i][j] = (f32x4){0.f, 0.f, 0.f, 0.f};

  auto stage = [&](int buf, int k0){
    gload16(aS0 + k0, &As[buf * 4096 + dA0]);
    gload16(aS1 + k0, &As[buf * 4096 + dA1]);
    gload16(bS0 + k0, &Bs[buf * 4096 + dA0]);
    gload16(bS1 + k0, &Bs[buf * 4096 + dA1]);
  };

  stage(0, 0);
  __syncthreads();
  int cur = 0;
  for (int k0 = 0; k0 < K; k0 += 32){
    if (k0 + 32 < K) stage(cur ^ 1, k0 + 32);
    bf16x8 af[4], bfv[4];
    #pragma unroll
    for (int mi = 0; mi < 4; ++mi)
      af[mi] = __builtin_bit_cast(bf16x8, *(const u16x8*)&As[cur * 4096 + aoff[mi]]);
    #pragma unroll
    for (int ni = 0; ni < 4; ++ni)
      bfv[ni] = __builtin_bit_cast(bf16x8, *(const u16x8*)&Bs[cur * 4096 + boff[ni]]);
    #pragma unroll
    for (int mi = 0; mi < 4; ++mi)
      #pragma unroll
      for (int ni = 0; ni < 4; ++ni)
        acc[mi][ni] = __builtin_amdgcn_mfma_f32_16x16x32_bf16(af[mi], bfv[ni], acc[mi][ni], 0, 0, 0);
    __syncthreads();          // drains vmcnt(0): next buffer landed
    cur ^= 1;
  }

  #pragma unroll
  for (int ni = 0; ni < 4; ++ni){
    int col = bn * 128 + wn * 64 + ni * 16 + fr;
    float bv = bias ? bias[col] : 0.f;
    #pragma unroll
    for (int mi = 0; mi < 4; ++mi){
      #pragma unroll
      for (int i = 0; i < 4; ++i){
        int row = row0 + wm * 64 + mi * 16 + fq * 4 + i;
        if (row < M){
          float v = acc[mi][ni][i] + bv;
          if (Cb) Cb[(size_t)row * ldc + col] = f2bf(v);
          else    Cf[(size_t)row * ldc + col] = v;
        }
      }
    }
  }
}

// plain GEMM (radial MLP); ldc == N
__global__ __launch_bounds__(256) void k_gemm_bt(
    const u16* __restrict__ A, int lda, const u16* __restrict__ B,
    const float* __restrict__ bias, float* __restrict__ Cf,
    u16* __restrict__ Cb, int ldc, int M, int N, int K)
{
  __shared__ u16 As[2 * 4096];
  __shared__ u16 Bs[2 * 4096];
  gemm_tile(A, lda, B, bias, Cf, Cb, ldc, M, N, K,
            blockIdx.y, blockIdx.x, As, Bs);
}

// segmented GEMM: up to 5 independent (A,B,C) GEMMs in one launch.
__global__ __launch_bounds__(256) void k_gemm_seg(Seg5 g)
{
  __shared__ u16 As[2 * 4096];
  __shared__ u16 Bs[2 * 4096];
  int wgid = swz8(blockIdx.x, g.nwg);
  Seg sg = g.s[4];
  if (wgid < g.s[4].blk0) sg = g.s[3];
  if (wgid < g.s[3].blk0) sg = g.s[2];
  if (wgid < g.s[2].blk0) sg = g.s[1];
  if (wgid < g.s[1].blk0) sg = g.s[0];
  int local = wgid - sg.blk0;
  int nbx = sg.N >> 7;
  int bn = local % nbx;
  int bm = local / nbx;
  gemm_tile(sg.A, sg.lda, sg.B, sg.bias, nullptr, sg.C, sg.N,
            sg.M, sg.N, sg.K, bm, bn, As, Bs);
}

// --------------------------- LayerNorm + SiLU ------------------------------
__global__ __launch_bounds__(256) void k_ln_silu(
    const float* __restrict__ in, const float* __restrict__ sc,
    const float* __restrict__ bb, u16* __restrict__ out)
{
  int e = blockIdx.x, t = threadIdx.x;
  float v = in[(size_t)e * 256 + t];
  float s1 = v, s2 = v * v;
  #pragma unroll
  for (int off = 32; off > 0; off >>= 1){
    s1 += __shfl_down(s1, off);
    s2 += __shfl_down(s2, off);
  }
  __shared__ float r1[4], r2[4];
  if ((t & 63) == 0){ r1[t >> 6] = s1; r2[t >> 6] = s2; }
  __syncthreads();
  float S1 = r1[0] + r1[1] + r1[2] + r1[3];
  float S2 = r2[0] + r2[1] + r2[2] + r2[3];
  float mu  = S1 * (1.f / 256.f);
  float var = S2 * (1.f / 256.f) - mu * mu;
  float nv = (v - mu) * rsqrtf(var + 1e-5f) * sc[t] + bb[t];
  out[(size_t)e * 256 + t] = f2bf(nv * sigm(nv));
}

// --------------------- Wigner forward (MFMA, permuted) ---------------------
__global__ __launch_bounds__(256) void k_wig_fwd(
    const u16* __restrict__ xT, const int* __restrict__ eidx,
    const float* __restrict__ wig, const u16* __restrict__ xrad,
    u16* __restrict__ msgS, const int* __restrict__ perm, int e0)
{
  __shared__ u16 WL[32 * 64];
  int el = blockIdx.x, tid = threadIdx.x;
  int eg = perm[e0 + el];
  int lane = tid & 63, w = tid >> 6;

  const float* wp = wig + (size_t)eg * 1421;
  for (int idx = tid; idx < 2048; idx += 256){
    int m = idx >> 6, k = idx & 63;
    float v = (m < 29 && k < 49) ? wp[m * 49 + k] : 0.f;
    WL[m * 64 + ((((k >> 3) ^ (m & 7))) << 3) + (k & 7)] = f2bf(v);
  }

  const int fr = lane & 15, fq = lane >> 4;
  const int colbase = w * 64;
  int node = eidx[((w >> 1) ? E_NUM : 0) + eg];
  const u16* xb = xT + (size_t)node * 8192;
  bf16x8 bfv[4][2];
  #pragma unroll
  for (int ct = 0; ct < 4; ++ct)
    #pragma unroll
    for (int ks = 0; ks < 2; ++ks){
      int cc = ((w & 1) * 64) + ct * 16 + fr;       // within-node column
      bfv[ct][ks] = __builtin_bit_cast(bf16x8,
          *(const u16x8*)(xb + cc * 64 + (ks * 4 + fq) * 8));
    }
  __syncthreads();

  bf16x8 af[2][2];
  #pragma unroll
  for (int mt = 0; mt < 2; ++mt)
    #pragma unroll
    for (int ks = 0; ks < 2; ++ks){
      int m = mt * 16 + fr;
      int g = ks * 4 + fq;
      af[mt][ks] = __builtin_bit_cast(bf16x8,
          *(const u16x8*)&WL[m * 64 + ((g ^ (m & 7)) << 3)]);
    }
  f32x4 acc[2][4];
  #pragma unroll
  for (int mt = 0; mt < 2; ++mt)
    #pragma unroll
    for (int ct = 0; ct < 4; ++ct) acc[mt][ct] = (f32x4){0.f,0.f,0.f,0.f};
  #pragma unroll
  for (int mt = 0; mt < 2; ++mt)
    #pragma unroll
    for (int ct = 0; ct < 4; ++ct)
      #pragma unroll
      for (int ks = 0; ks < 2; ++ks)
        acc[mt][ct] = __builtin_amdgcn_mfma_f32_16x16x32_bf16(
            af[mt][ks], bfv[ct][ks], acc[mt][ct], 0, 0, 0);

  const u16* xr = xrad + (size_t)el * 4608;
  u16* o = msgS + (size_t)el * 7424;
  #pragma unroll
  for (int mt = 0; mt < 2; ++mt)
    #pragma unroll
    for (int ct = 0; ct < 4; ++ct){
      int col = colbase + ct * 16 + fr;
      #pragma unroll
      for (int r = 0; r < 4; ++r){
        int m = mt * 16 + fq * 4 + r;
        if (m < 29){
          int rr = (m < 13) ? m : (m < 24 ? m - 6 : m - 11);
          o[m * 256 + col] = f2bf(acc[mt][ct][r] * bf2f(xr[rr * 256 + col]));
        }
      }
    }
}

// -------------------- gate + recombine (conv1, u16x8) ----------------------
__global__ __launch_bounds__(256) void k_gate(
    const u16* __restrict__ c1m0, const u16* __restrict__ y10, const u16* __restrict__ y11,
    const u16* __restrict__ y20, const u16* __restrict__ y21, u16* __restrict__ msg2)
{
  int e = blockIdx.x, t = threadIdx.x;
  __shared__ float g[768];
  const u16* gp = c1m0 + (size_t)e * 1664;
  if (t < 96){
    u16x8 v = *(const u16x8*)(gp + t * 8);
    #pragma unroll
    for (int i = 0; i < 8; ++i) g[t * 8 + i] = sigm(bf2f(v[i]));
  }
  __syncthreads();
  const u16* x0 = gp + 768;
  const u16* a0 = y10 + (size_t)e * 1536;
  const u16* a1 = y11 + (size_t)e * 1536;
  const u16* b0 = y20 + (size_t)e * 1280;
  const u16* b1 = y21 + (size_t)e * 1280;
  u16* o = msg2 + (size_t)e * 3712;
  const int grp = (t & 15) * 8;
  for (int r = t >> 4; r < 29; r += 16){
    u16x8 outv;
    if (r == 0){
      u16x8 v = *(const u16x8*)(x0 + grp);
      #pragma unroll
      for (int i = 0; i < 8; ++i){ float f = bf2f(v[i]); outv[i] = f2bf(f * sigm(f)); }
    } else if (r < 7){
      u16x8 v = *(const u16x8*)(x0 + r * 128 + grp);
      #pragma unroll
      for (int i = 0; i < 8; ++i)
        outv[i] = f2bf(bf2f(v[i]) * g[(r - 1) * 128 + grp + i]);
    } else if (r < 19){
      int k = (r < 13) ? r - 7 : r - 13;
      // real: a0[k]-a1[768+k] ; imag: a1[k]+a0[768+k]
      u16x8 va = *(const u16x8*)(a0 + ((r < 13) ? k * 128 : 768 + k * 128) + grp);
      u16x8 vb = *(const u16x8*)(a1 + ((r < 13) ? 768 + k * 128 : k * 128) + grp);
      #pragma unroll
      for (int i = 0; i < 8; ++i){
        float fa = bf2f(va[i]), fb = bf2f(vb[i]);
        float val = (r < 13) ? (fa - fb) : (fb + fa);
        outv[i] = f2bf(val * g[k * 128 + grp + i]);
      }
    } else {
      int k = (r < 24) ? r - 19 : r - 24;
      u16x8 va = *(const u16x8*)(b0 + ((r < 24) ? k * 128 : 640 + k * 128) + grp);
      u16x8 vb = *(const u16x8*)(b1 + ((r < 24) ? 640 + k * 128 : k * 128) + grp);
      #pragma unroll
      for (int i = 0; i < 8; ++i){
        float fa = bf2f(va[i]), fb = bf2f(vb[i]);
        float val = (r < 24) ? (fa - fb) : (fb + fa);
        outv[i] = f2bf(val * g[(1 + k) * 128 + grp + i]);
      }
    }
    *(u16x8*)(o + r * 128 + grp) = outv;
  }
}

// -------- recombine2 + envelope -> msg3T (c,m); LDS-staged u16x8 reads -----
__global__ __launch_bounds__(128) void k_recomb2(
    const u16* __restrict__ m3x0, const u16* __restrict__ z10, const u16* __restrict__ z11,
    const u16* __restrict__ z20, const u16* __restrict__ z21, const float* __restrict__ env,
    u16* __restrict__ msg3T, const int* __restrict__ perm, int e0)
{
  __shared__ u16 s[6528];   // x0@0(896) a0@896(1536) a1@2432(1536) b0@3968(1280) b1@5248(1280)
  int e = blockIdx.x, c = threadIdx.x;
  {
    const u16* px0 = m3x0 + (size_t)e * 896;
    const u16* pa0 = z10 + (size_t)e * 1536;
    const u16* pa1 = z11 + (size_t)e * 1536;
    const u16* pb0 = z20 + (size_t)e * 1280;
    const u16* pb1 = z21 + (size_t)e * 1280;
    for (int v = c; v < 112; v += 128) *(u16x8*)(&s[v * 8])        = *(const u16x8*)(px0 + v * 8);
    for (int v = c; v < 192; v += 128) *(u16x8*)(&s[896 + v * 8])  = *(const u16x8*)(pa0 + v * 8);
    for (int v = c; v < 192; v += 128) *(u16x8*)(&s[2432 + v * 8]) = *(const u16x8*)(pa1 + v * 8);
    for (int v = c; v < 160; v += 128) *(u16x8*)(&s[3968 + v * 8]) = *(const u16x8*)(pb0 + v * 8);
    for (int v = c; v < 160; v += 128) *(u16x8*)(&s[5248 + v * 8]) = *(const u16x8*)(pb1 + v * 8);
  }
  __syncthreads();
  float ev = env[perm[e0 + e]];
  const u16* x0 = s;
  const u16* a0 = s + 896;
  const u16* a1 = s + 2432;
  const u16* b0 = s + 3968;
  const u16* b1 = s + 5248;
  u16 v[32];
  #pragma unroll
  for (int r = 0; r < 7; ++r) v[r] = f2bf(bf2f(x0[r * 128 + c]) * ev);
  #pragma unroll
  for (int k = 0; k < 6; ++k){
    float orr = bf2f(a0[k * 128 + c]) - bf2f(a1[768 + k * 128 + c]);
    float oii = bf2f(a1[k * 128 + c]) + bf2f(a0[768 + k * 128 + c]);
    v[7 + k]  = f2bf(orr * ev);
    v[13 + k] = f2bf(oii * ev);
  }
  #pragma unroll
  for (int k = 0; k < 5; ++k){
    float orr = bf2f(b0[k * 128 + c]) - bf2f(b1[640 + k * 128 + c]);
    float oii = bf2f(b1[k * 128 + c]) + bf2f(b0[640 + k * 128 + c]);
    v[19 + k] = f2bf(orr * ev);
    v[24 + k] = f2bf(oii * ev);
  }
  v[29] = 0; v[30] = 0; v[31] = 0;
  u16* o = msg3T + (size_t)e * 4096 + c * 32;
  #pragma unroll
  for (int q = 0; q < 4; ++q)
    *(u16x8*)(o + q * 8) = *(const u16x8*)(&v[q * 8]);
}

// ------------- Wigner inverse (MFMA, run-gather) + store/scatter -----------
__global__ __launch_bounds__(256) void k_wig_inv(
    const u16* __restrict__ msg3T, const float* __restrict__ winv,
    const int* __restrict__ eidx, float* __restrict__ out,
    const int* __restrict__ perm, int e0, int cm)
{
  __shared__ u16 WV[64 * 32];
  int el = blockIdx.x, tid = threadIdx.x;
  int i = e0 + el;
  int d = eidx[E_NUM + perm[i]];
  if (el > 0 && eidx[E_NUM + perm[i - 1]] == d) return;   // not a run start
  bool tail = (el == 0) && (e0 > 0) && (eidx[E_NUM + perm[e0 - 1]] == d);
  int lane = tid & 63, w = tid >> 6;
  const int fr = lane & 15, fq = lane >> 4;
  const int jr = w * 16 + fr;

  f32x4 acc[8];
  #pragma unroll
  for (int ct = 0; ct < 8; ++ct) acc[ct] = (f32x4){0.f,0.f,0.f,0.f};

  int tend = e0 + cm;
  int t = i;
  for (; t < tend; ++t){
    int pe = perm[t];
    if (t > i && eidx[E_NUM + pe] != d) break;
    __syncthreads();
    const float* wp = winv + (size_t)pe * 1421;
    for (int idx = tid; idx < 2048; idx += 256){
      int j = idx >> 5, m = idx & 31;
      float v = (j < 49 && m < 29) ? wp[j * 29 + m] : 0.f;
      WV[j * 32 + (((m >> 3) ^ (j & 3)) << 3) + (m & 7)] = f2bf(v);
    }
    __syncthreads();
    bf16x8 a = __builtin_bit_cast(bf16x8,
        *(const u16x8*)&WV[jr * 32 + ((fq ^ (jr & 3)) << 3)]);
    const u16* bp = msg3T + (size_t)(t - e0) * 4096;
    #pragma unroll
    for (int ct = 0; ct < 8; ++ct){
      bf16x8 b = __builtin_bit_cast(bf16x8,
          *(const u16x8*)(bp + (ct * 16 + fr) * 32 + fq * 8));
      acc[ct] = __builtin_amdgcn_mfma_f32_16x16x32_bf16(a, b, acc[ct], 0, 0, 0);
    }
  }
  // head: the run continues into the next chunk
  bool head = (t == tend) && (tend < E_NUM) && (eidx[E_NUM + perm[tend]] == d);
  bool atom = tail || head;      // block-uniform

  float* op = out + (size_t)d * 6272;
  if (atom){
    #pragma unroll
    for (int ct = 0; ct < 8; ++ct){
      int c = ct * 16 + fr;
      #pragma unroll
      for (int r = 0; r < 4; ++r){
        int j = w * 16 + fq * 4 + r;
        if (j < 49) atomicAdd(op + j * 128 + c, acc[ct][r]);
      }
    }
  } else {
    #pragma unroll
    for (int ct = 0; ct < 8; ++ct){
      int c = ct * 16 + fr;
      #pragma unroll
      for (int r = 0; r < 4; ++r){
        int j = w * 16 + fq * 4 + r;
        if (j < 49) op[j * 128 + c] = acc[ct][r];
      }
    }
  }
}

// ---------------------------------------------------------------------------
extern "C" void kernel_launch(void* const* d_in, const int* in_sizes, int n_in,
                              void* d_out, int out_size, void* d_ws, size_t ws_size,
                              hipStream_t stream)
{
  (void)in_sizes; (void)n_in;
  const float* x       = (const float*)d_in[0];
  const float* x_edge  = (const float*)d_in[1];
  const int*   eidx    = (const int*)d_in[3];
  const float* wig     = (const float*)d_in[4];
  const float* wig_inv = (const float*)d_in[5];
  const float* env     = (const float*)d_in[6];
  const float* rad_w0  = (const float*)d_in[7];
  const float* rad_b0  = (const float*)d_in[8];
  const float* ln0_s   = (const float*)d_in[9];
  const float* ln0_b   = (const float*)d_in[10];
  const float* rad_w1  = (const float*)d_in[11];
  const float* rad_b1  = (const float*)d_in[12];
  const float* ln1_s   = (const float*)d_in[13];
  const float* ln1_b   = (const float*)d_in[14];
  const float* rad_w2  = (const float*)d_in[15];
  const float* rad_b2  = (const float*)d_in[16];
  const float* c1w0    = (const float*)d_in[17];
  const float* c1b0    = (const float*)d_in[18];
  const float* c1w1    = (const float*)d_in[19];
  const float* c1w2    = (const float*)d_in[20];
  const float* c2w0    = (const float*)d_in[21];
  const float* c2b0    = (const float*)d_in[22];
  const float* c2w1    = (const float*)d_in[23];
  const float* c2w2    = (const float*)d_in[24];
  float* out = (float*)d_out;

  char* base = (char*)d_ws;
  size_t off = 0;
  auto alloc = [&](size_t bytes) -> char* {
    off = (off + 255) & ~(size_t)255;
    char* r = base + off;
    off += bytes;
    return r;
  };

  // ---- fixed area: bf16 weights (~22.2 MB) + xT (78 MB) + sort arrays ----
  u16* wtR0  = (u16*)alloc((size_t)256  * 128  * 2);
  u16* wtR1  = (u16*)alloc((size_t)256  * 256  * 2);
  u16* wtR2  = (u16*)alloc((size_t)4608 * 256  * 2);
  u16* wtC10 = (u16*)alloc((size_t)1664 * 1792 * 2);
  u16* wtC11 = (u16*)alloc((size_t)1536 * 1536 * 2);
  u16* wtC12 = (u16*)alloc((size_t)1280 * 1280 * 2);
  u16* wtC20 = (u16*)alloc((size_t)896  * 896  * 2);
  u16* wtC21 = (u16*)alloc((size_t)1536 * 768  * 2);
  u16* wtC22 = (u16*)alloc((size_t)1280 * 640  * 2);
  u16* xT    = (u16*)alloc((size_t)NN * 8192 * 2);
  int* cnt   = (int*)alloc(NN * 4);
  int* soff  = (int*)alloc(NN * 4);
  int* perm  = (int*)alloc(E_NUM * 4);

  // ---- chunk size from remaining workspace (40,960 B per edge) ----
  size_t fixed_end = (off + 65536) & ~(size_t)65535;
  size_t avail = (ws_size > fixed_end + (1u << 20)) ? (ws_size - fixed_end - (1u << 20)) : 0;
  long CH0 = (long)(avail / 40960);
  if (CH0 > E_NUM) CH0 = E_NUM;
  if (CH0 < 64) CH0 = 64;
  int nch = (int)((E_NUM + CH0 - 1) / CH0);
  int CH = (E_NUM + nch - 1) / nch;          // equalized chunks
  if (CH > CH0) CH = (int)CH0;

  off = fixed_end;
  const size_t C = (size_t)CH;
  u16*   xe   = (u16*)alloc(C * 128 * 2);
  float* tmp  = (float*)alloc(C * 256 * 4);
  u16*   h0   = (u16*)alloc(C * 256 * 2);
  u16*   h1   = (u16*)alloc(C * 256 * 2);
  u16* region1 = (u16*)alloc(C * 4608 * 2);   // xrad -> msg2
  u16* region2 = (u16*)alloc(C * 7424 * 2);   // msgS -> conv2 outs
  u16* region3 = (u16*)alloc(C * 7296 * 2);   // conv1 outs -> msg3T
  u16* xrad = region1;
  u16* msg2 = region1;
  u16* msgS = region2;
  u16* m3x0 = region2;                 // (C,896)
  u16* z10  = region2 + C * 896;       // (C,1536)
  u16* z11  = region2 + C * 2432;      // (C,1536)
  u16* z20  = region2 + C * 3968;      // (C,1280)
  u16* z21  = region2 + C * 5248;      // (C,1280)
  u16* c1m0b = region3;                // (C,1664)
  u16* y10   = region3 + C * 1664;     // (C,1536)
  u16* y11   = region3 + C * 3200;     // (C,1536)
  u16* y20   = region3 + C * 4736;     // (C,1280)
  u16* y21   = region3 + C * 6016;     // (C,1280)
  u16* msg3T = region3;                // (C,4096) transposed (c,m)

  hipMemsetAsync(d_out, 0, (size_t)out_size * sizeof(float), stream);
  hipMemsetAsync(cnt, 0, NN * 4, stream);

  // dst counting sort -> perm ; x transpose
  k_hist<<<(E_NUM + 255) / 256, 256, 0, stream>>>(eidx, cnt);
  k_scan<<<1, 256, 0, stream>>>(cnt, soff);
  k_scatter<<<(E_NUM + 255) / 256, 256, 0, stream>>>(eidx, soff, perm);
  k_xpose<<<NN, 256, 0, stream>>>(x, xT);

  auto tw = [&](const float* in, u16* o, int K, int N){
    k_transpose_w<<<dim3(N / 32, K / 32), 256, 0, stream>>>(in, o, K, N);
  };
  tw(rad_w0, wtR0, 128, 256);
  tw(rad_w1, wtR1, 256, 256);
  tw(rad_w2, wtR2, 256, 4608);
  tw(c1w0, wtC10, 1792, 1664);
  tw(c1w1, wtC11, 1536, 1536);
  tw(c1w2, wtC12, 1280, 1280);
  tw(c2w0, wtC20, 896, 896);
  tw(c2w1, wtC21, 768, 1536);
  tw(c2w2, wtC22, 640, 1280);

  auto gemm = [&](const u16* A, int lda, const u16* B, const float* bias,
                  float* Cf, u16* Cb, int ldc, int M, int N, int K){
    k_gemm_bt<<<dim3(N / 128, (M + 127) / 128), 256, 0, stream>>>(
        A, lda, B, bias, Cf, Cb, ldc, M, N, K);
  };

  for (int e0 = 0; e0 < E_NUM; e0 += CH){
    int cm = E_NUM - e0 < CH ? E_NUM - e0 : CH;
    int mb = (cm + 127) / 128;

    k_gather_xe<<<cm, 128, 0, stream>>>(x_edge, perm, xe, e0);

    // radial MLP
    gemm(xe, 128, wtR0, rad_b0, tmp, nullptr, 256, cm, 256, 128);
    k_ln_silu<<<cm, 256, 0, stream>>>(tmp, ln0_s, ln0_b, h0);
    gemm(h0, 256, wtR1, rad_b1, tmp, nullptr, 256, cm, 256, 256);
    k_ln_silu<<<cm, 256, 0, stream>>>(tmp, ln1_s, ln1_b, h1);
    gemm(h1, 256, wtR2, rad_b2, nullptr, xrad, 4608, cm, 4608, 256);

    // wigner forward (MFMA, B-frags from global xT)
    k_wig_fwd<<<cm, 256, 0, stream>>>(xT, eidx, wig, xrad, msgS, perm, e0);

    // conv1: one segmented launch (m0 + y10 + y11 + y20 + y21)
    {
      Seg5 g;
      int b = 0;
      auto mk = [&](const u16* A, const u16* B, u16* Cb, const float* bias,
                    int N, int K) -> Seg {
        Seg s{A, B, Cb, bias, cm, N, K, 7424, b};
        b += (N >> 7) * mb;
        return s;
      };
      g.s[0] = mk(msgS,        wtC10, c1m0b, c1b0,   1664, 1792);
      g.s[1] = mk(msgS + 1792, wtC11, y10,   nullptr, 1536, 1536);
      g.s[2] = mk(msgS + 3328, wtC11, y11,   nullptr, 1536, 1536);
      g.s[3] = mk(msgS + 4864, wtC12, y20,   nullptr, 1280, 1280);
      g.s[4] = mk(msgS + 6144, wtC12, y21,   nullptr, 1280, 1280);
      g.nwg = b;
      k_gemm_seg<<<b, 256, 0, stream>>>(g);
    }

    k_gate<<<cm, 256, 0, stream>>>(c1m0b, y10, y11, y20, y21, msg2);

    // conv2: one segmented launch (m0 + z10 + z11 + z20 + z21)
    {
      Seg5 g;
      int b = 0;
      auto mk = [&](const u16* A, const u16* B, u16* Cb, const float* bias,
                    int N, int K) -> Seg {
        Seg s{A, B, Cb, bias, cm, N, K, 3712, b};
        b += (N >> 7) * mb;
        return s;
      };
      g.s[0] = mk(msg2,        wtC20, m3x0, c2b0,   896,  896);
      g.s[1] = mk(msg2 + 896,  wtC21, z10,  nullptr, 1536, 768);
      g.s[2] = mk(msg2 + 1664, wtC21, z11,  nullptr, 1536, 768);
      g.s[3] = mk(msg2 + 2432, wtC22, z20,  nullptr, 1280, 640);
      g.s[4] = mk(msg2 + 3072, wtC22, z21,  nullptr, 1280, 640);
      g.nwg = b;
      k_gemm_seg<<<b, 256, 0, stream>>>(g);
    }

    k_recomb2<<<cm, 128, 0, stream>>>(m3x0, z10, z11, z20, z21, env, msg3T, perm, e0);

    // wigner inverse + run-gather (stores for contained runs, atomics at cuts)
    k_wig_inv<<<cm, 256, 0, stream>>>(msg3T, wig_inv, eidx, out, perm, e0, cm);
  }
}

// Round 13
// 2355.531 us; speedup vs baseline: 1.0549x; 1.0549x over previous
//
#include <hip/hip_runtime.h>
#include <stdint.h>

// ---------------------------------------------------------------------------
// Edgewise (eSCN SO(2) conv block), MI355X gfx950.
// Round 13: (1) radial MLP gemm+LN+SiLU fused (k_gemm_ln, full-row blocks,
// shfl+LDS row reduction) — kills tmp f32 traffic and 4 launches;
// (2) wig_inv: node-indexed grid (cnt/soff run bounds), double-buffered W
// staging, 1 barrier/edge. GEMM core stays round-9 2-phase (751 TF plateau).
// ---------------------------------------------------------------------------

#define E_NUM   20000
#define NN      5000

typedef uint16_t u16;
typedef __bf16  bf16x8 __attribute__((ext_vector_type(8)));
typedef float   f32x4  __attribute__((ext_vector_type(4)));
typedef uint16_t u16x8 __attribute__((ext_vector_type(8)));

__device__ __forceinline__ float bf2f(u16 h){
  uint32_t u = ((uint32_t)h) << 16;
  return __builtin_bit_cast(float, u);
}
__device__ __forceinline__ u16 f2bf(float f){
  uint32_t u = __builtin_bit_cast(uint32_t, f);
  u += 0x7fffu + ((u >> 16) & 1u);
  return (u16)(u >> 16);
}
__device__ __forceinline__ float sigm(float x){ return 1.f / (1.f + __expf(-x)); }

__device__ __forceinline__ void gload16(const void* g, void* l){
  __builtin_amdgcn_global_load_lds(
      (const __attribute__((address_space(1))) void*)g,
      (__attribute__((address_space(3))) void*)l, 16, 0, 0);
}

// bijective XCD swizzle (m204): contiguous wgid ranges per XCD
__device__ __forceinline__ int swz8(int orig, int nwg){
  int q = nwg >> 3, r = nwg & 7;
  int x = orig & 7, p = orig >> 3;
  int base = (x < r) ? x * (q + 1) : r * (q + 1) + (x - r) * q;
  return base + p;
}

// ----------------------- dst counting sort ---------------------------------
__global__ void k_hist(const int* __restrict__ eidx, int* __restrict__ cnt){
  int e = blockIdx.x * 256 + threadIdx.x;
  if (e < E_NUM) atomicAdd(&cnt[eidx[E_NUM + e]], 1);
}
__global__ __launch_bounds__(256) void k_scan(const int* __restrict__ cnt,
                                              int* __restrict__ off){
  __shared__ int part[256];
  int t = threadIdx.x;
  int s = 0;
  #pragma unroll
  for (int i = 0; i < 20; ++i){
    int idx = t * 20 + i;
    if (idx < NN) s += cnt[idx];
  }
  part[t] = s;
  __syncthreads();
  if (t == 0){
    int run = 0;
    for (int i = 0; i < 256; ++i){ int v = part[i]; part[i] = run; run += v; }
  }
  __syncthreads();
  int run = part[t];
  #pragma unroll
  for (int i = 0; i < 20; ++i){
    int idx = t * 20 + i;
    if (idx < NN){ off[idx] = run; run += cnt[idx]; }
  }
}
__global__ void k_scatter(const int* __restrict__ eidx, int* __restrict__ off,
                          int* __restrict__ perm){
  int e = blockIdx.x * 256 + threadIdx.x;
  if (e < E_NUM){
    int pos = atomicAdd(&off[eidx[E_NUM + e]], 1);
    perm[pos] = e;
  }
}

// --------------------------- weight transpose ------------------------------
__global__ void k_transpose_w(const float* __restrict__ in, u16* __restrict__ out,
                              int K, int N){
  __shared__ float t[32][33];
  int nb = blockIdx.x * 32, kb = blockIdx.y * 32;
  int tx = threadIdx.x & 31, ty = threadIdx.x >> 5;   // 32x8
  for (int i = ty; i < 32; i += 8)
    t[i][tx] = in[(size_t)(kb + i) * N + (nb + tx)];
  __syncthreads();
  for (int i = ty; i < 32; i += 8)
    out[(size_t)(nb + i) * K + (kb + tx)] = f2bf(t[tx][i]);
}

// ------------- x -> xT bf16, [node][c=128][k=64 padded], once --------------
__global__ __launch_bounds__(256) void k_xpose(const float* __restrict__ x,
                                               u16* __restrict__ xT){
  __shared__ float t[6272];
  int n = blockIdx.x, tid = threadIdx.x;
  const float* xp = x + (size_t)n * 6272;
  for (int i = tid; i < 6272; i += 256) t[i] = xp[i];
  __syncthreads();
  int c = tid >> 1;
  int kh = (tid & 1) * 32;
  u16* o = xT + (size_t)n * 8192 + c * 64 + kh;
  #pragma unroll
  for (int q = 0; q < 4; ++q){
    u16x8 h;
    #pragma unroll
    for (int i = 0; i < 8; ++i){
      int k = kh + q * 8 + i;
      h[i] = (k < 49) ? f2bf(t[k * 128 + c]) : (u16)0;
    }
    *(u16x8*)(o + q * 8) = h;
  }
}

// gather x_edge rows in permuted order -> bf16
__global__ void k_gather_xe(const float* __restrict__ x_edge,
                            const int* __restrict__ perm,
                            u16* __restrict__ xe, int e0){
  int el = blockIdx.x, c = threadIdx.x;
  int pe = perm[e0 + el];
  xe[(size_t)el * 128 + c] = f2bf(x_edge[(size_t)pe * 128 + c]);
}

// ---------------------- GEMM core (round-9 structure) ----------------------
struct Seg {
  const u16* A; const u16* B; u16* C; const float* bias;
  int M, N, K, lda, blk0;
};
struct Seg5 { Seg s[5]; int nwg; };

__device__ __forceinline__ void gemm_tile(
    const u16* __restrict__ A, int lda, const u16* __restrict__ B,
    const float* __restrict__ bias, float* __restrict__ Cf,
    u16* __restrict__ Cb, int ldc, int M, int N, int K,
    int bm, int bn, u16* As /*2*4096*/, u16* Bs /*2*4096*/)
{
  const int tid  = threadIdx.x;
  const int lane = tid & 63;
  const int wave = tid >> 6;
  const int wm = wave >> 1, wn = wave & 1;
  const int fr = lane & 15, fq = lane >> 4;
  const int row0 = bm * 128;

  const int lr  = lane >> 2;
  const int lg  = lane & 3;
  const int rA0 = wave * 32 + lr;
  const int rA1 = rA0 + 16;
  const int g0  = lg ^ ((rA0 >> 1) & 3);
  const int g1  = lg ^ ((rA1 >> 1) & 3);
  int gra0 = row0 + rA0; if (gra0 > M - 1) gra0 = M - 1;
  int gra1 = row0 + rA1; if (gra1 > M - 1) gra1 = M - 1;
  const u16* aS0 = A + (size_t)gra0 * lda + g0 * 8;
  const u16* aS1 = A + (size_t)gra1 * lda + g1 * 8;
  const u16* bS0 = B + (size_t)(bn * 128 + rA0) * K + g0 * 8;
  const u16* bS1 = B + (size_t)(bn * 128 + rA1) * K + g1 * 8;
  const int dA0 = (wave * 32) * 32;
  const int dA1 = (wave * 32 + 16) * 32;

  int aoff[4], boff[4];
  #pragma unroll
  for (int mi = 0; mi < 4; ++mi){
    int r = wm * 64 + mi * 16 + fr;
    aoff[mi] = r * 32 + (fq ^ ((r >> 1) & 3)) * 8;
  }
  #pragma unroll
  for (int ni = 0; ni < 4; ++ni){
    int r = wn * 64 + ni * 16 + fr;
    boff[ni] = r * 32 + (fq ^ ((r >> 1) & 3)) * 8;
  }

  f32x4 acc[4][4];
  #pragma unroll
  for (int i = 0; i < 4; ++i)
    #pragma unroll
    for (int j = 0; j < 4; ++j) acc[i][j] = (f32x4){0.f, 0.f, 0.f, 0.f};

  auto stage = [&](int buf, int k0){
    gload16(aS0 + k0, &As[buf * 4096 + dA0]);
    gload16(aS1 + k0, &As[buf * 4096 + dA1]);
    gload16(bS0 + k0, &Bs[buf * 4096 + dA0]);
    gload16(bS1 + k0, &Bs[buf * 4096 + dA1]);
  };

  stage(0, 0);
  __syncthreads();
  int cur = 0;
  for (int k0 = 0; k0 < K; k0 += 32){
    if (k0 + 32 < K) stage(cur ^ 1, k0 + 32);
    bf16x8 af[4], bfv[4];
    #pragma unroll
    for (int mi = 0; mi < 4; ++mi)
      af[mi] = __builtin_bit_cast(bf16x8, *(const u16x8*)&As[cur * 4096 + aoff[mi]]);
    #pragma unroll
    for (int ni = 0; ni < 4; ++ni)
      bfv[ni] = __builtin_bit_cast(bf16x8, *(const u16x8*)&Bs[cur * 4096 + boff[ni]]);
    #pragma unroll
    for (int mi = 0; mi < 4; ++mi)
      #pragma unroll
      for (int ni = 0; ni < 4; ++ni)
        acc[mi][ni] = __builtin_amdgcn_mfma_f32_16x16x32_bf16(af[mi], bfv[ni], acc[mi][ni], 0, 0, 0);
    __syncthreads();          // drains vmcnt(0): next buffer landed
    cur ^= 1;
  }

  #pragma unroll
  for (int ni = 0; ni < 4; ++ni){
    int col = bn * 128 + wn * 64 + ni * 16 + fr;
    float bv = bias ? bias[col] : 0.f;
    #pragma unroll
    for (int mi = 0; mi < 4; ++mi){
      #pragma unroll
      for (int i = 0; i < 4; ++i){
        int row = row0 + wm * 64 + mi * 16 + fq * 4 + i;
        if (row < M){
          float v = acc[mi][ni][i] + bv;
          if (Cb) Cb[(size_t)row * ldc + col] = f2bf(v);
          else    Cf[(size_t)row * ldc + col] = v;
        }
      }
    }
  }
}

// plain GEMM; ldc == N
__global__ __launch_bounds__(256) void k_gemm_bt(
    const u16* __restrict__ A, int lda, const u16* __restrict__ B,
    const float* __restrict__ bias, float* __restrict__ Cf,
    u16* __restrict__ Cb, int ldc, int M, int N, int K)
{
  __shared__ u16 As[2 * 4096];
  __shared__ u16 Bs[2 * 4096];
  gemm_tile(A, lda, B, bias, Cf, Cb, ldc, M, N, K,
            blockIdx.y, blockIdx.x, As, Bs);
}

// segmented GEMM: up to 5 independent (A,B,C) GEMMs in one launch.
__global__ __launch_bounds__(256) void k_gemm_seg(Seg5 g)
{
  __shared__ u16 As[2 * 4096];
  __shared__ u16 Bs[2 * 4096];
  int wgid = swz8(blockIdx.x, g.nwg);
  Seg sg = g.s[4];
  if (wgid < g.s[4].blk0) sg = g.s[3];
  if (wgid < g.s[3].blk0) sg = g.s[2];
  if (wgid < g.s[2].blk0) sg = g.s[1];
  if (wgid < g.s[1].blk0) sg = g.s[0];
  int local = wgid - sg.blk0;
  int nbx = sg.N >> 7;
  int bn = local % nbx;
  int bm = local / nbx;
  gemm_tile(sg.A, sg.lda, sg.B, sg.bias, nullptr, sg.C, sg.N,
            sg.M, sg.N, sg.K, bm, bn, As, Bs);
}

// ------------------ fused GEMM(N=256) + LayerNorm + SiLU -------------------
// 512 threads (8 waves). Block = 128 rows x 256 cols: wave w covers rows
// (w&1)*64, cols (w>>1)*64. LN across the full 256-col row via 16-lane
// shfl_xor reduce + 4-quarter LDS reduce. Output bf16 (M,256).
__global__ __launch_bounds__(512) void k_gemm_ln(
    const u16* __restrict__ A, int lda, const u16* __restrict__ B /*(256,K)*/,
    const float* __restrict__ bias, const float* __restrict__ lns,
    const float* __restrict__ lnb, u16* __restrict__ out, int M, int K)
{
  __shared__ u16 As[2][4096];    // 128 x 32
  __shared__ u16 Bs[2][8192];    // 256 x 32
  __shared__ float rsum[128][4], rsq[128][4];
  const int tid = threadIdx.x, lane = tid & 63, w = tid >> 6;
  const int fr = lane & 15, fq = lane >> 4;
  const int bm = blockIdx.x, row0 = bm * 128;

  // staging: A rows w*16..+15 (1 load), B rows w*32..+31 (2 loads)
  const int lr = lane >> 2, lg = lane & 3;
  int rA = w * 16 + lr;
  int gA = lg ^ ((rA >> 1) & 3);
  int grA = row0 + rA; if (grA > M - 1) grA = M - 1;
  const u16* aS = A + (size_t)grA * lda + gA * 8;
  int rB0 = w * 32 + lr, rB1 = rB0 + 16;
  int gB0 = lg ^ ((rB0 >> 1) & 3), gB1 = lg ^ ((rB1 >> 1) & 3);
  const u16* bS0 = B + (size_t)rB0 * K + gB0 * 8;
  const u16* bS1 = B + (size_t)rB1 * K + gB1 * 8;
  const int dA  = (w * 16) * 32;
  const int dB0 = (w * 32) * 32;
  const int dB1 = (w * 32 + 16) * 32;

  int aoff[4], boff[4];
  #pragma unroll
  for (int mi = 0; mi < 4; ++mi){
    int r = (w & 1) * 64 + mi * 16 + fr;
    aoff[mi] = r * 32 + (fq ^ ((r >> 1) & 3)) * 8;
  }
  #pragma unroll
  for (int ni = 0; ni < 4; ++ni){
    int ccol = (w >> 1) * 64 + ni * 16 + fr;
    boff[ni] = ccol * 32 + (fq ^ ((ccol >> 1) & 3)) * 8;
  }

  f32x4 acc[4][4];
  #pragma unroll
  for (int i = 0; i < 4; ++i)
    #pragma unroll
    for (int j = 0; j < 4; ++j) acc[i][j] = (f32x4){0.f, 0.f, 0.f, 0.f};

  auto stage = [&](int buf, int k0){
    gload16(aS + k0, &As[buf][dA]);
    gload16(bS0 + k0, &Bs[buf][dB0]);
    gload16(bS1 + k0, &Bs[buf][dB1]);
  };

  stage(0, 0);
  __syncthreads();
  int cur = 0;
  for (int k0 = 0; k0 < K; k0 += 32){
    if (k0 + 32 < K) stage(cur ^ 1, k0 + 32);
    bf16x8 af[4], bfv[4];
    #pragma unroll
    for (int mi = 0; mi < 4; ++mi)
      af[mi] = __builtin_bit_cast(bf16x8, *(const u16x8*)&As[cur][aoff[mi]]);
    #pragma unroll
    for (int ni = 0; ni < 4; ++ni)
      bfv[ni] = __builtin_bit_cast(bf16x8, *(const u16x8*)&Bs[cur][boff[ni]]);
    #pragma unroll
    for (int mi = 0; mi < 4; ++mi)
      #pragma unroll
      for (int ni = 0; ni < 4; ++ni)
        acc[mi][ni] = __builtin_amdgcn_mfma_f32_16x16x32_bf16(af[mi], bfv[ni], acc[mi][ni], 0, 0, 0);
    __syncthreads();
    cur ^= 1;
  }

  // epilogue: add bias, per-row LN over 256 cols, SiLU, store bf16
  const int cq = w >> 1;
  float bv[4], sc[4], bb[4];
  #pragma unroll
  for (int ni = 0; ni < 4; ++ni){
    int col = cq * 64 + ni * 16 + fr;
    bv[ni] = bias[col]; sc[ni] = lns[col]; bb[ni] = lnb[col];
  }
  #pragma unroll
  for (int mi = 0; mi < 4; ++mi){
    #pragma unroll
    for (int i = 0; i < 4; ++i){
      float s1 = 0.f, s2 = 0.f;
      #pragma unroll
      for (int ni = 0; ni < 4; ++ni){
        float v = acc[mi][ni][i] + bv[ni];
        s1 += v; s2 += v * v;
      }
      #pragma unroll
      for (int off = 1; off < 16; off <<= 1){
        s1 += __shfl_xor(s1, off);
        s2 += __shfl_xor(s2, off);
      }
      if (fr == 0){
        int r = (w & 1) * 64 + mi * 16 + fq * 4 + i;
        rsum[r][cq] = s1; rsq[r][cq] = s2;
      }
    }
  }
  __syncthreads();
  #pragma unroll
  for (int mi = 0; mi < 4; ++mi){
    #pragma unroll
    for (int i = 0; i < 4; ++i){
      int r = (w & 1) * 64 + mi * 16 + fq * 4 + i;
      float S1 = rsum[r][0] + rsum[r][1] + rsum[r][2] + rsum[r][3];
      float S2 = rsq[r][0] + rsq[r][1] + rsq[r][2] + rsq[r][3];
      float mu  = S1 * (1.f / 256.f);
      float var = S2 * (1.f / 256.f) - mu * mu;
      float rs  = rsqrtf(var + 1e-5f);
      int row = row0 + r;
      if (row < M){
        #pragma unroll
        for (int ni = 0; ni < 4; ++ni){
          int col = cq * 64 + ni * 16 + fr;
          float nv = (acc[mi][ni][i] + bv[ni] - mu) * rs * sc[ni] + bb[ni];
          out[(size_t)row * 256 + col] = f2bf(nv * sigm(nv));
        }
      }
    }
  }
}

// --------------------- Wigner forward (MFMA, permuted) ---------------------
__global__ __launch_bounds__(256) void k_wig_fwd(
    const u16* __restrict__ xT, const int* __restrict__ eidx,
    const float* __restrict__ wig, const u16* __restrict__ xrad,
    u16* __restrict__ msgS, const int* __restrict__ perm, int e0)
{
  __shared__ u16 WL[32 * 64];
  int el = blockIdx.x, tid = threadIdx.x;
  int eg = perm[e0 + el];
  int lane = tid & 63, w = tid >> 6;

  const float* wp = wig + (size_t)eg * 1421;
  for (int idx = tid; idx < 2048; idx += 256){
    int m = idx >> 6, k = idx & 63;
    float v = (m < 29 && k < 49) ? wp[m * 49 + k] : 0.f;
    WL[m * 64 + ((((k >> 3) ^ (m & 7))) << 3) + (k & 7)] = f2bf(v);
  }

  const int fr = lane & 15, fq = lane >> 4;
  const int colbase = w * 64;
  int node = eidx[((w >> 1) ? E_NUM : 0) + eg];
  const u16* xb = xT + (size_t)node * 8192;
  bf16x8 bfv[4][2];
  #pragma unroll
  for (int ct = 0; ct < 4; ++ct)
    #pragma unroll
    for (int ks = 0; ks < 2; ++ks){
      int cc = ((w & 1) * 64) + ct * 16 + fr;       // within-node column
      bfv[ct][ks] = __builtin_bit_cast(bf16x8,
          *(const u16x8*)(xb + cc * 64 + (ks * 4 + fq) * 8));
    }
  __syncthreads();

  bf16x8 af[2][2];
  #pragma unroll
  for (int mt = 0; mt < 2; ++mt)
    #pragma unroll
    for (int ks = 0; ks < 2; ++ks){
      int m = mt * 16 + fr;
      int g = ks * 4 + fq;
      af[mt][ks] = __builtin_bit_cast(bf16x8,
          *(const u16x8*)&WL[m * 64 + ((g ^ (m & 7)) << 3)]);
    }
  f32x4 acc[2][4];
  #pragma unroll
  for (int mt = 0; mt < 2; ++mt)
    #pragma unroll
    for (int ct = 0; ct < 4; ++ct) acc[mt][ct] = (f32x4){0.f,0.f,0.f,0.f};
  #pragma unroll
  for (int mt = 0; mt < 2; ++mt)
    #pragma unroll
    for (int ct = 0; ct < 4; ++ct)
      #pragma unroll
      for (int ks = 0; ks < 2; ++ks)
        acc[mt][ct] = __builtin_amdgcn_mfma_f32_16x16x32_bf16(
            af[mt][ks], bfv[ct][ks], acc[mt][ct], 0, 0, 0);

  const u16* xr = xrad + (size_t)el * 4608;
  u16* o = msgS + (size_t)el * 7424;
  #pragma unroll
  for (int mt = 0; mt < 2; ++mt)
    #pragma unroll
    for (int ct = 0; ct < 4; ++ct){
      int col = colbase + ct * 16 + fr;
      #pragma unroll
      for (int r = 0; r < 4; ++r){
        int m = mt * 16 + fq * 4 + r;
        if (m < 29){
          int rr = (m < 13) ? m : (m < 24 ? m - 6 : m - 11);
          o[m * 256 + col] = f2bf(acc[mt][ct][r] * bf2f(xr[rr * 256 + col]));
        }
      }
    }
}

// -------------------- gate + recombine (conv1, u16x8) ----------------------
__global__ __launch_bounds__(256) void k_gate(
    const u16* __restrict__ c1m0, const u16* __restrict__ y10, const u16* __restrict__ y11,
    const u16* __restrict__ y20, const u16* __restrict__ y21, u16* __restrict__ msg2)
{
  int e = blockIdx.x, t = threadIdx.x;
  __shared__ float g[768];
  const u16* gp = c1m0 + (size_t)e * 1664;
  if (t < 96){
    u16x8 v = *(const u16x8*)(gp + t * 8);
    #pragma unroll
    for (int i = 0; i < 8; ++i) g[t * 8 + i] = sigm(bf2f(v[i]));
  }
  __syncthreads();
  const u16* x0 = gp + 768;
  const u16* a0 = y10 + (size_t)e * 1536;
  const u16* a1 = y11 + (size_t)e * 1536;
  const u16* b0 = y20 + (size_t)e * 1280;
  const u16* b1 = y21 + (size_t)e * 1280;
  u16* o = msg2 + (size_t)e * 3712;
  const int grp = (t & 15) * 8;
  for (int r = t >> 4; r < 29; r += 16){
    u16x8 outv;
    if (r == 0){
      u16x8 v = *(const u16x8*)(x0 + grp);
      #pragma unroll
      for (int i = 0; i < 8; ++i){ float f = bf2f(v[i]); outv[i] = f2bf(f * sigm(f)); }
    } else if (r < 7){
      u16x8 v = *(const u16x8*)(x0 + r * 128 + grp);
      #pragma unroll
      for (int i = 0; i < 8; ++i)
        outv[i] = f2bf(bf2f(v[i]) * g[(r - 1) * 128 + grp + i]);
    } else if (r < 19){
      int k = (r < 13) ? r - 7 : r - 13;
      u16x8 va = *(const u16x8*)(a0 + ((r < 13) ? k * 128 : 768 + k * 128) + grp);
      u16x8 vb = *(const u16x8*)(a1 + ((r < 13) ? 768 + k * 128 : k * 128) + grp);
      #pragma unroll
      for (int i = 0; i < 8; ++i){
        float fa = bf2f(va[i]), fb = bf2f(vb[i]);
        float val = (r < 13) ? (fa - fb) : (fb + fa);
        outv[i] = f2bf(val * g[k * 128 + grp + i]);
      }
    } else {
      int k = (r < 24) ? r - 19 : r - 24;
      u16x8 va = *(const u16x8*)(b0 + ((r < 24) ? k * 128 : 640 + k * 128) + grp);
      u16x8 vb = *(const u16x8*)(b1 + ((r < 24) ? 640 + k * 128 : k * 128) + grp);
      #pragma unroll
      for (int i = 0; i < 8; ++i){
        float fa = bf2f(va[i]), fb = bf2f(vb[i]);
        float val = (r < 24) ? (fa - fb) : (fb + fa);
        outv[i] = f2bf(val * g[(1 + k) * 128 + grp + i]);
      }
    }
    *(u16x8*)(o + r * 128 + grp) = outv;
  }
}

// -------- recombine2 + envelope -> msg3T (c,m); LDS-staged u16x8 reads -----
__global__ __launch_bounds__(128) void k_recomb2(
    const u16* __restrict__ m3x0, const u16* __restrict__ z10, const u16* __restrict__ z11,
    const u16* __restrict__ z20, const u16* __restrict__ z21, const float* __restrict__ env,
    u16* __restrict__ msg3T, const int* __restrict__ perm, int e0)
{
  __shared__ u16 s[6528];
  int e = blockIdx.x, c = threadIdx.x;
  {
    const u16* px0 = m3x0 + (size_t)e * 896;
    const u16* pa0 = z10 + (size_t)e * 1536;
    const u16* pa1 = z11 + (size_t)e * 1536;
    const u16* pb0 = z20 + (size_t)e * 1280;
    const u16* pb1 = z21 + (size_t)e * 1280;
    for (int v = c; v < 112; v += 128) *(u16x8*)(&s[v * 8])        = *(const u16x8*)(px0 + v * 8);
    for (int v = c; v < 192; v += 128) *(u16x8*)(&s[896 + v * 8])  = *(const u16x8*)(pa0 + v * 8);
    for (int v = c; v < 192; v += 128) *(u16x8*)(&s[2432 + v * 8]) = *(const u16x8*)(pa1 + v * 8);
    for (int v = c; v < 160; v += 128) *(u16x8*)(&s[3968 + v * 8]) = *(const u16x8*)(pb0 + v * 8);
    for (int v = c; v < 160; v += 128) *(u16x8*)(&s[5248 + v * 8]) = *(const u16x8*)(pb1 + v * 8);
  }
  __syncthreads();
  float ev = env[perm[e0 + e]];
  const u16* x0 = s;
  const u16* a0 = s + 896;
  const u16* a1 = s + 2432;
  const u16* b0 = s + 3968;
  const u16* b1 = s + 5248;
  u16 v[32];
  #pragma unroll
  for (int r = 0; r < 7; ++r) v[r] = f2bf(bf2f(x0[r * 128 + c]) * ev);
  #pragma unroll
  for (int k = 0; k < 6; ++k){
    float orr = bf2f(a0[k * 128 + c]) - bf2f(a1[768 + k * 128 + c]);
    float oii = bf2f(a1[k * 128 + c]) + bf2f(a0[768 + k * 128 + c]);
    v[7 + k]  = f2bf(orr * ev);
    v[13 + k] = f2bf(oii * ev);
  }
  #pragma unroll
  for (int k = 0; k < 5; ++k){
    float orr = bf2f(b0[k * 128 + c]) - bf2f(b1[640 + k * 128 + c]);
    float oii = bf2f(b1[k * 128 + c]) + bf2f(b0[640 + k * 128 + c]);
    v[19 + k] = f2bf(orr * ev);
    v[24 + k] = f2bf(oii * ev);
  }
  v[29] = 0; v[30] = 0; v[31] = 0;
  u16* o = msg3T + (size_t)e * 4096 + c * 32;
  #pragma unroll
  for (int q = 0; q < 4; ++q)
    *(u16x8*)(o + q * 8) = *(const u16x8*)(&v[q * 8]);
}

// --------- Wigner inverse (MFMA, node-indexed run-gather, W dbuf) ----------
// Block d handles node d's run [soff[d]-cnt[d], soff[d]) clipped to the
// chunk [e0, e0+cm). Plain stores when the full run is in this chunk;
// atomicAdd when clipped (straddling node). W double-buffered in LDS.
__global__ __launch_bounds__(256) void k_wig_inv(
    const u16* __restrict__ msg3T, const float* __restrict__ winv,
    const int* __restrict__ cnt, const int* __restrict__ soff,
    float* __restrict__ out, const int* __restrict__ perm, int e0, int cm)
{
  __shared__ u16 WV[2][2048];
  int d = blockIdx.x, tid = threadIdx.x;
  int cn = cnt[d];
  if (cn == 0) return;
  int runEnd = soff[d];           // post-scatter soff = run end
  int runStart = runEnd - cn;
  int start = runStart < e0 ? e0 : runStart;
  int end   = runEnd > e0 + cm ? e0 + cm : runEnd;
  if (start >= end) return;
  bool atom = (start != runStart) || (end != runEnd);

  int lane = tid & 63, w = tid >> 6;
  const int fr = lane & 15, fq = lane >> 4;
  const int jr = w * 16 + fr;

  auto stageW = [&](int buf, int pe){
    const float* wp = winv + (size_t)pe * 1421;
    for (int idx = tid; idx < 2048; idx += 256){
      int j = idx >> 5, m = idx & 31;
      float v = (j < 49 && m < 29) ? wp[j * 29 + m] : 0.f;
      WV[buf][j * 32 + (((m >> 3) ^ (j & 3)) << 3) + (m & 7)] = f2bf(v);
    }
  };

  f32x4 acc[8];
  #pragma unroll
  for (int ct = 0; ct < 8; ++ct) acc[ct] = (f32x4){0.f,0.f,0.f,0.f};

  stageW(0, perm[start]);
  __syncthreads();
  int b = 0;
  for (int t = start; t < end; ++t){
    if (t + 1 < end) stageW(b ^ 1, perm[t + 1]);
    bf16x8 a = __builtin_bit_cast(bf16x8,
        *(const u16x8*)&WV[b][jr * 32 + ((fq ^ (jr & 3)) << 3)]);
    const u16* bp = msg3T + (size_t)(t - e0) * 4096;
    #pragma unroll
    for (int ct = 0; ct < 8; ++ct){
      bf16x8 bo = __builtin_bit_cast(bf16x8,
          *(const u16x8*)(bp + (ct * 16 + fr) * 32 + fq * 8));
      acc[ct] = __builtin_amdgcn_mfma_f32_16x16x32_bf16(a, bo, acc[ct], 0, 0, 0);
    }
    __syncthreads();
    b ^= 1;
  }

  float* op = out + (size_t)d * 6272;
  if (atom){
    #pragma unroll
    for (int ct = 0; ct < 8; ++ct){
      int c = ct * 16 + fr;
      #pragma unroll
      for (int r = 0; r < 4; ++r){
        int j = w * 16 + fq * 4 + r;
        if (j < 49) atomicAdd(op + j * 128 + c, acc[ct][r]);
      }
    }
  } else {
    #pragma unroll
    for (int ct = 0; ct < 8; ++ct){
      int c = ct * 16 + fr;
      #pragma unroll
      for (int r = 0; r < 4; ++r){
        int j = w * 16 + fq * 4 + r;
        if (j < 49) op[j * 128 + c] = acc[ct][r];
      }
    }
  }
}

// ---------------------------------------------------------------------------
extern "C" void kernel_launch(void* const* d_in, const int* in_sizes, int n_in,
                              void* d_out, int out_size, void* d_ws, size_t ws_size,
                              hipStream_t stream)
{
  (void)in_sizes; (void)n_in;
  const float* x       = (const float*)d_in[0];
  const float* x_edge  = (const float*)d_in[1];
  const int*   eidx    = (const int*)d_in[3];
  const float* wig     = (const float*)d_in[4];
  const float* wig_inv = (const float*)d_in[5];
  const float* env     = (const float*)d_in[6];
  const float* rad_w0  = (const float*)d_in[7];
  const float* rad_b0  = (const float*)d_in[8];
  const float* ln0_s   = (const float*)d_in[9];
  const float* ln0_b   = (const float*)d_in[10];
  const float* rad_w1  = (const float*)d_in[11];
  const float* rad_b1  = (const float*)d_in[12];
  const float* ln1_s   = (const float*)d_in[13];
  const float* ln1_b   = (const float*)d_in[14];
  const float* rad_w2  = (const float*)d_in[15];
  const float* rad_b2  = (const float*)d_in[16];
  const float* c1w0    = (const float*)d_in[17];
  const float* c1b0    = (const float*)d_in[18];
  const float* c1w1    = (const float*)d_in[19];
  const float* c1w2    = (const float*)d_in[20];
  const float* c2w0    = (const float*)d_in[21];
  const float* c2b0    = (const float*)d_in[22];
  const float* c2w1    = (const float*)d_in[23];
  const float* c2w2    = (const float*)d_in[24];
  float* out = (float*)d_out;

  char* base = (char*)d_ws;
  size_t off = 0;
  auto alloc = [&](size_t bytes) -> char* {
    off = (off + 255) & ~(size_t)255;
    char* r = base + off;
    off += bytes;
    return r;
  };

  // ---- fixed area: bf16 weights (~22.2 MB) + xT (78 MB) + sort arrays ----
  u16* wtR0  = (u16*)alloc((size_t)256  * 128  * 2);
  u16* wtR1  = (u16*)alloc((size_t)256  * 256  * 2);
  u16* wtR2  = (u16*)alloc((size_t)4608 * 256  * 2);
  u16* wtC10 = (u16*)alloc((size_t)1664 * 1792 * 2);
  u16* wtC11 = (u16*)alloc((size_t)1536 * 1536 * 2);
  u16* wtC12 = (u16*)alloc((size_t)1280 * 1280 * 2);
  u16* wtC20 = (u16*)alloc((size_t)896  * 896  * 2);
  u16* wtC21 = (u16*)alloc((size_t)1536 * 768  * 2);
  u16* wtC22 = (u16*)alloc((size_t)1280 * 640  * 2);
  u16* xT    = (u16*)alloc((size_t)NN * 8192 * 2);
  int* cnt   = (int*)alloc(NN * 4);
  int* soff  = (int*)alloc(NN * 4);
  int* perm  = (int*)alloc(E_NUM * 4);

  // ---- chunk size from remaining workspace (40,960 B per edge kept) ----
  size_t fixed_end = (off + 65536) & ~(size_t)65535;
  size_t avail = (ws_size > fixed_end + (1u << 20)) ? (ws_size - fixed_end - (1u << 20)) : 0;
  long CH0 = (long)(avail / 40960);
  if (CH0 > E_NUM) CH0 = E_NUM;
  if (CH0 < 64) CH0 = 64;
  int nch = (int)((E_NUM + CH0 - 1) / CH0);
  int CH = (E_NUM + nch - 1) / nch;          // equalized chunks
  if (CH > CH0) CH = (int)CH0;

  off = fixed_end;
  const size_t C = (size_t)CH;
  u16*   xe   = (u16*)alloc(C * 128 * 2);
  u16*   h0   = (u16*)alloc(C * 256 * 2);
  u16*   h1   = (u16*)alloc(C * 256 * 2);
  u16* region1 = (u16*)alloc(C * 4608 * 2);   // xrad -> msg2
  u16* region2 = (u16*)alloc(C * 7424 * 2);   // msgS -> conv2 outs
  u16* region3 = (u16*)alloc(C * 7296 * 2);   // conv1 outs -> msg3T
  u16* xrad = region1;
  u16* msg2 = region1;
  u16* msgS = region2;
  u16* m3x0 = region2;                 // (C,896)
  u16* z10  = region2 + C * 896;       // (C,1536)
  u16* z11  = region2 + C * 2432;      // (C,1536)
  u16* z20  = region2 + C * 3968;      // (C,1280)
  u16* z21  = region2 + C * 5248;      // (C,1280)
  u16* c1m0b = region3;                // (C,1664)
  u16* y10   = region3 + C * 1664;     // (C,1536)
  u16* y11   = region3 + C * 3200;     // (C,1536)
  u16* y20   = region3 + C * 4736;     // (C,1280)
  u16* y21   = region3 + C * 6016;     // (C,1280)
  u16* msg3T = region3;                // (C,4096) transposed (c,m)

  hipMemsetAsync(d_out, 0, (size_t)out_size * sizeof(float), stream);
  hipMemsetAsync(cnt, 0, NN * 4, stream);

  // dst counting sort -> perm ; x transpose
  k_hist<<<(E_NUM + 255) / 256, 256, 0, stream>>>(eidx, cnt);
  k_scan<<<1, 256, 0, stream>>>(cnt, soff);
  k_scatter<<<(E_NUM + 255) / 256, 256, 0, stream>>>(eidx, soff, perm);
  k_xpose<<<NN, 256, 0, stream>>>(x, xT);

  auto tw = [&](const float* in, u16* o, int K, int N){
    k_transpose_w<<<dim3(N / 32, K / 32), 256, 0, stream>>>(in, o, K, N);
  };
  tw(rad_w0, wtR0, 128, 256);
  tw(rad_w1, wtR1, 256, 256);
  tw(rad_w2, wtR2, 256, 4608);
  tw(c1w0, wtC10, 1792, 1664);
  tw(c1w1, wtC11, 1536, 1536);
  tw(c1w2, wtC12, 1280, 1280);
  tw(c2w0, wtC20, 896, 896);
  tw(c2w1, wtC21, 768, 1536);
  tw(c2w2, wtC22, 640, 1280);

  for (int e0 = 0; e0 < E_NUM; e0 += CH){
    int cm = E_NUM - e0 < CH ? E_NUM - e0 : CH;
    int mb = (cm + 127) / 128;

    k_gather_xe<<<cm, 128, 0, stream>>>(x_edge, perm, xe, e0);

    // radial MLP: 2 fused gemm+LN+SiLU + final wide gemm
    k_gemm_ln<<<mb, 512, 0, stream>>>(xe, 128, wtR0, rad_b0, ln0_s, ln0_b, h0, cm, 128);
    k_gemm_ln<<<mb, 512, 0, stream>>>(h0, 256, wtR1, rad_b1, ln1_s, ln1_b, h1, cm, 256);
    k_gemm_bt<<<dim3(4608 / 128, mb), 256, 0, stream>>>(
        h1, 256, wtR2, rad_b2, nullptr, xrad, 4608, cm, 4608, 256);

    // wigner forward (MFMA, B-frags from global xT)
    k_wig_fwd<<<cm, 256, 0, stream>>>(xT, eidx, wig, xrad, msgS, perm, e0);

    // conv1: one segmented launch
    {
      Seg5 g;
      int b = 0;
      auto mk = [&](const u16* A, const u16* B, u16* Cb, const float* bias,
                    int N, int K) -> Seg {
        Seg s{A, B, Cb, bias, cm, N, K, 7424, b};
        b += (N >> 7) * mb;
        return s;
      };
      g.s[0] = mk(msgS,        wtC10, c1m0b, c1b0,   1664, 1792);
      g.s[1] = mk(msgS + 1792, wtC11, y10,   nullptr, 1536, 1536);
      g.s[2] = mk(msgS + 3328, wtC11, y11,   nullptr, 1536, 1536);
      g.s[3] = mk(msgS + 4864, wtC12, y20,   nullptr, 1280, 1280);
      g.s[4] = mk(msgS + 6144, wtC12, y21,   nullptr, 1280, 1280);
      g.nwg = b;
      k_gemm_seg<<<b, 256, 0, stream>>>(g);
    }

    k_gate<<<cm, 256, 0, stream>>>(c1m0b, y10, y11, y20, y21, msg2);

    // conv2: one segmented launch
    {
      Seg5 g;
      int b = 0;
      auto mk = [&](const u16* A, const u16* B, u16* Cb, const float* bias,
                    int N, int K) -> Seg {
        Seg s{A, B, Cb, bias, cm, N, K, 3712, b};
        b += (N >> 7) * mb;
        return s;
      };
      g.s[0] = mk(msg2,        wtC20, m3x0, c2b0,   896,  896);
      g.s[1] = mk(msg2 + 896,  wtC21, z10,  nullptr, 1536, 768);
      g.s[2] = mk(msg2 + 1664, wtC21, z11,  nullptr, 1536, 768);
      g.s[3] = mk(msg2 + 2432, wtC22, z20,  nullptr, 1280, 640);
      g.s[4] = mk(msg2 + 3072, wtC22, z21,  nullptr, 1280, 640);
      g.nwg = b;
      k_gemm_seg<<<b, 256, 0, stream>>>(g);
    }

    k_recomb2<<<cm, 128, 0, stream>>>(m3x0, z10, z11, z20, z21, env, msg3T, perm, e0);

    // wigner inverse: node-indexed run-gather, W dbuf
    k_wig_inv<<<NN, 256, 0, stream>>>(msg3T, wig_inv, cnt, soff, out, perm, e0, cm);
  }
}

// Round 14
// 2318.383 us; speedup vs baseline: 1.0718x; 1.0160x over previous
//
#include <hip/hip_runtime.h>
#include <stdint.h>

// ---------------------------------------------------------------------------
// Edgewise (eSCN SO(2) conv block), MI355X gfx950.
// Round 14: GEMM core -> 3-buffer counted-vmcnt pipeline (48 KB LDS keeps
// 3 blocks/CU; ONE raw s_barrier per K-step; vmcnt(4) waits for the oldest
// stage only, so one stage stays in flight across the barrier).
// Rest identical to round 13 (fused gemm_ln, node-indexed dbuf wig_inv,
// segmented conv launches, xT, dst-sorted run-gather).
// ---------------------------------------------------------------------------

#define E_NUM   20000
#define NN      5000

typedef uint16_t u16;
typedef __bf16  bf16x8 __attribute__((ext_vector_type(8)));
typedef float   f32x4  __attribute__((ext_vector_type(4)));
typedef uint16_t u16x8 __attribute__((ext_vector_type(8)));

__device__ __forceinline__ float bf2f(u16 h){
  uint32_t u = ((uint32_t)h) << 16;
  return __builtin_bit_cast(float, u);
}
__device__ __forceinline__ u16 f2bf(float f){
  uint32_t u = __builtin_bit_cast(uint32_t, f);
  u += 0x7fffu + ((u >> 16) & 1u);
  return (u16)(u >> 16);
}
__device__ __forceinline__ float sigm(float x){ return 1.f / (1.f + __expf(-x)); }

__device__ __forceinline__ void gload16(const void* g, void* l){
  __builtin_amdgcn_global_load_lds(
      (const __attribute__((address_space(1))) void*)g,
      (__attribute__((address_space(3))) void*)l, 16, 0, 0);
}

// bijective XCD swizzle (m204): contiguous wgid ranges per XCD
__device__ __forceinline__ int swz8(int orig, int nwg){
  int q = nwg >> 3, r = nwg & 7;
  int x = orig & 7, p = orig >> 3;
  int base = (x < r) ? x * (q + 1) : r * (q + 1) + (x - r) * q;
  return base + p;
}

// ----------------------- dst counting sort ---------------------------------
__global__ void k_hist(const int* __restrict__ eidx, int* __restrict__ cnt){
  int e = blockIdx.x * 256 + threadIdx.x;
  if (e < E_NUM) atomicAdd(&cnt[eidx[E_NUM + e]], 1);
}
__global__ __launch_bounds__(256) void k_scan(const int* __restrict__ cnt,
                                              int* __restrict__ off){
  __shared__ int part[256];
  int t = threadIdx.x;
  int s = 0;
  #pragma unroll
  for (int i = 0; i < 20; ++i){
    int idx = t * 20 + i;
    if (idx < NN) s += cnt[idx];
  }
  part[t] = s;
  __syncthreads();
  if (t == 0){
    int run = 0;
    for (int i = 0; i < 256; ++i){ int v = part[i]; part[i] = run; run += v; }
  }
  __syncthreads();
  int run = part[t];
  #pragma unroll
  for (int i = 0; i < 20; ++i){
    int idx = t * 20 + i;
    if (idx < NN){ off[idx] = run; run += cnt[idx]; }
  }
}
__global__ void k_scatter(const int* __restrict__ eidx, int* __restrict__ off,
                          int* __restrict__ perm){
  int e = blockIdx.x * 256 + threadIdx.x;
  if (e < E_NUM){
    int pos = atomicAdd(&off[eidx[E_NUM + e]], 1);
    perm[pos] = e;
  }
}

// --------------------------- weight transpose ------------------------------
__global__ void k_transpose_w(const float* __restrict__ in, u16* __restrict__ out,
                              int K, int N){
  __shared__ float t[32][33];
  int nb = blockIdx.x * 32, kb = blockIdx.y * 32;
  int tx = threadIdx.x & 31, ty = threadIdx.x >> 5;   // 32x8
  for (int i = ty; i < 32; i += 8)
    t[i][tx] = in[(size_t)(kb + i) * N + (nb + tx)];
  __syncthreads();
  for (int i = ty; i < 32; i += 8)
    out[(size_t)(nb + i) * K + (kb + tx)] = f2bf(t[tx][i]);
}

// ------------- x -> xT bf16, [node][c=128][k=64 padded], once --------------
__global__ __launch_bounds__(256) void k_xpose(const float* __restrict__ x,
                                               u16* __restrict__ xT){
  __shared__ float t[6272];
  int n = blockIdx.x, tid = threadIdx.x;
  const float* xp = x + (size_t)n * 6272;
  for (int i = tid; i < 6272; i += 256) t[i] = xp[i];
  __syncthreads();
  int c = tid >> 1;
  int kh = (tid & 1) * 32;
  u16* o = xT + (size_t)n * 8192 + c * 64 + kh;
  #pragma unroll
  for (int q = 0; q < 4; ++q){
    u16x8 h;
    #pragma unroll
    for (int i = 0; i < 8; ++i){
      int k = kh + q * 8 + i;
      h[i] = (k < 49) ? f2bf(t[k * 128 + c]) : (u16)0;
    }
    *(u16x8*)(o + q * 8) = h;
  }
}

// gather x_edge rows in permuted order -> bf16
__global__ void k_gather_xe(const float* __restrict__ x_edge,
                            const int* __restrict__ perm,
                            u16* __restrict__ xe, int e0){
  int el = blockIdx.x, c = threadIdx.x;
  int pe = perm[e0 + el];
  xe[(size_t)el * 128 + c] = f2bf(x_edge[(size_t)pe * 128 + c]);
}

// ------------- GEMM core (3-buffer counted-vmcnt pipeline) -----------------
struct Seg {
  const u16* A; const u16* B; u16* C; const float* bias;
  int M, N, K, lda, blk0;
};
struct Seg5 { Seg s[5]; int nwg; };

__device__ __forceinline__ void gemm_tile(
    const u16* __restrict__ A, int lda, const u16* __restrict__ B,
    const float* __restrict__ bias, float* __restrict__ Cf,
    u16* __restrict__ Cb, int ldc, int M, int N, int K,
    int bm, int bn, u16* As /*3*4096*/, u16* Bs /*3*4096*/)
{
  const int tid  = threadIdx.x;
  const int lane = tid & 63;
  const int wave = tid >> 6;
  const int wm = wave >> 1, wn = wave & 1;
  const int fr = lane & 15, fq = lane >> 4;
  const int row0 = bm * 128;

  const int lr  = lane >> 2;
  const int lg  = lane & 3;
  const int rA0 = wave * 32 + lr;
  const int rA1 = rA0 + 16;
  const int g0  = lg ^ ((rA0 >> 1) & 3);
  const int g1  = lg ^ ((rA1 >> 1) & 3);
  int gra0 = row0 + rA0; if (gra0 > M - 1) gra0 = M - 1;
  int gra1 = row0 + rA1; if (gra1 > M - 1) gra1 = M - 1;
  const u16* aS0 = A + (size_t)gra0 * lda + g0 * 8;
  const u16* aS1 = A + (size_t)gra1 * lda + g1 * 8;
  const u16* bS0 = B + (size_t)(bn * 128 + rA0) * K + g0 * 8;
  const u16* bS1 = B + (size_t)(bn * 128 + rA1) * K + g1 * 8;
  const int dA0 = (wave * 32) * 32;
  const int dA1 = (wave * 32 + 16) * 32;

  int aoff[4], boff[4];
  #pragma unroll
  for (int mi = 0; mi < 4; ++mi){
    int r = wm * 64 + mi * 16 + fr;
    aoff[mi] = r * 32 + (fq ^ ((r >> 1) & 3)) * 8;
  }
  #pragma unroll
  for (int ni = 0; ni < 4; ++ni){
    int r = wn * 64 + ni * 16 + fr;
    boff[ni] = r * 32 + (fq ^ ((r >> 1) & 3)) * 8;
  }

  f32x4 acc[4][4];
  #pragma unroll
  for (int i = 0; i < 4; ++i)
    #pragma unroll
    for (int j = 0; j < 4; ++j) acc[i][j] = (f32x4){0.f, 0.f, 0.f, 0.f};

  auto stage = [&](int buf, int k0){
    gload16(aS0 + k0, &As[buf * 4096 + dA0]);
    gload16(aS1 + k0, &As[buf * 4096 + dA1]);
    gload16(bS0 + k0, &Bs[buf * 4096 + dA0]);
    gload16(bS1 + k0, &Bs[buf * 4096 + dA1]);
  };

  const int nk = K >> 5;
  stage(0, 0);
  if (nk > 1) stage(1, 32);

  int buf = 0;
  for (int t = 0; t < nk; ++t){
    // wait for stage(t): if stage(t+1) was issued, allow its 4 loads in flight
    if (t + 1 < nk) asm volatile("s_waitcnt vmcnt(4)" ::: "memory");
    else            asm volatile("s_waitcnt vmcnt(0)" ::: "memory");
    __builtin_amdgcn_s_barrier();          // all waves: buf[t%3] ready,
    asm volatile("" ::: "memory");         // and buf[(t+2)%3] free (readers done)
    if (t + 2 < nk) stage((t + 2 == 2) ? 2 : ((buf + 2) % 3), (t + 2) * 32);

    const int cb = buf * 4096;
    bf16x8 af[4], bfv[4];
    #pragma unroll
    for (int mi = 0; mi < 4; ++mi)
      af[mi] = __builtin_bit_cast(bf16x8, *(const u16x8*)&As[cb + aoff[mi]]);
    #pragma unroll
    for (int ni = 0; ni < 4; ++ni)
      bfv[ni] = __builtin_bit_cast(bf16x8, *(const u16x8*)&Bs[cb + boff[ni]]);
    #pragma unroll
    for (int mi = 0; mi < 4; ++mi)
      #pragma unroll
      for (int ni = 0; ni < 4; ++ni)
        acc[mi][ni] = __builtin_amdgcn_mfma_f32_16x16x32_bf16(af[mi], bfv[ni], acc[mi][ni], 0, 0, 0);
    asm volatile("" ::: "memory");
    buf = (buf + 1) % 3;
  }

  #pragma unroll
  for (int ni = 0; ni < 4; ++ni){
    int col = bn * 128 + wn * 64 + ni * 16 + fr;
    float bv = bias ? bias[col] : 0.f;
    #pragma unroll
    for (int mi = 0; mi < 4; ++mi){
      #pragma unroll
      for (int i = 0; i < 4; ++i){
        int row = row0 + wm * 64 + mi * 16 + fq * 4 + i;
        if (row < M){
          float v = acc[mi][ni][i] + bv;
          if (Cb) Cb[(size_t)row * ldc + col] = f2bf(v);
          else    Cf[(size_t)row * ldc + col] = v;
        }
      }
    }
  }
}

// plain GEMM; ldc == N
__global__ __launch_bounds__(256) void k_gemm_bt(
    const u16* __restrict__ A, int lda, const u16* __restrict__ B,
    const float* __restrict__ bias, float* __restrict__ Cf,
    u16* __restrict__ Cb, int ldc, int M, int N, int K)
{
  __shared__ u16 As[3 * 4096];
  __shared__ u16 Bs[3 * 4096];
  gemm_tile(A, lda, B, bias, Cf, Cb, ldc, M, N, K,
            blockIdx.y, blockIdx.x, As, Bs);
}

// segmented GEMM: up to 5 independent (A,B,C) GEMMs in one launch.
__global__ __launch_bounds__(256) void k_gemm_seg(Seg5 g)
{
  __shared__ u16 As[3 * 4096];
  __shared__ u16 Bs[3 * 4096];
  int wgid = swz8(blockIdx.x, g.nwg);
  Seg sg = g.s[4];
  if (wgid < g.s[4].blk0) sg = g.s[3];
  if (wgid < g.s[3].blk0) sg = g.s[2];
  if (wgid < g.s[2].blk0) sg = g.s[1];
  if (wgid < g.s[1].blk0) sg = g.s[0];
  int local = wgid - sg.blk0;
  int nbx = sg.N >> 7;
  int bn = local % nbx;
  int bm = local / nbx;
  gemm_tile(sg.A, sg.lda, sg.B, sg.bias, nullptr, sg.C, sg.N,
            sg.M, sg.N, sg.K, bm, bn, As, Bs);
}

// ------------------ fused GEMM(N=256) + LayerNorm + SiLU -------------------
__global__ __launch_bounds__(512) void k_gemm_ln(
    const u16* __restrict__ A, int lda, const u16* __restrict__ B /*(256,K)*/,
    const float* __restrict__ bias, const float* __restrict__ lns,
    const float* __restrict__ lnb, u16* __restrict__ out, int M, int K)
{
  __shared__ u16 As[2][4096];    // 128 x 32
  __shared__ u16 Bs[2][8192];    // 256 x 32
  __shared__ float rsum[128][4], rsq[128][4];
  const int tid = threadIdx.x, lane = tid & 63, w = tid >> 6;
  const int fr = lane & 15, fq = lane >> 4;
  const int bm = blockIdx.x, row0 = bm * 128;

  const int lr = lane >> 2, lg = lane & 3;
  int rA = w * 16 + lr;
  int gA = lg ^ ((rA >> 1) & 3);
  int grA = row0 + rA; if (grA > M - 1) grA = M - 1;
  const u16* aS = A + (size_t)grA * lda + gA * 8;
  int rB0 = w * 32 + lr, rB1 = rB0 + 16;
  int gB0 = lg ^ ((rB0 >> 1) & 3), gB1 = lg ^ ((rB1 >> 1) & 3);
  const u16* bS0 = B + (size_t)rB0 * K + gB0 * 8;
  const u16* bS1 = B + (size_t)rB1 * K + gB1 * 8;
  const int dA  = (w * 16) * 32;
  const int dB0 = (w * 32) * 32;
  const int dB1 = (w * 32 + 16) * 32;

  int aoff[4], boff[4];
  #pragma unroll
  for (int mi = 0; mi < 4; ++mi){
    int r = (w & 1) * 64 + mi * 16 + fr;
    aoff[mi] = r * 32 + (fq ^ ((r >> 1) & 3)) * 8;
  }
  #pragma unroll
  for (int ni = 0; ni < 4; ++ni){
    int ccol = (w >> 1) * 64 + ni * 16 + fr;
    boff[ni] = ccol * 32 + (fq ^ ((ccol >> 1) & 3)) * 8;
  }

  f32x4 acc[4][4];
  #pragma unroll
  for (int i = 0; i < 4; ++i)
    #pragma unroll
    for (int j = 0; j < 4; ++j) acc[i][j] = (f32x4){0.f, 0.f, 0.f, 0.f};

  auto stage = [&](int buf, int k0){
    gload16(aS + k0, &As[buf][dA]);
    gload16(bS0 + k0, &Bs[buf][dB0]);
    gload16(bS1 + k0, &Bs[buf][dB1]);
  };

  stage(0, 0);
  __syncthreads();
  int cur = 0;
  for (int k0 = 0; k0 < K; k0 += 32){
    if (k0 + 32 < K) stage(cur ^ 1, k0 + 32);
    bf16x8 af[4], bfv[4];
    #pragma unroll
    for (int mi = 0; mi < 4; ++mi)
      af[mi] = __builtin_bit_cast(bf16x8, *(const u16x8*)&As[cur][aoff[mi]]);
    #pragma unroll
    for (int ni = 0; ni < 4; ++ni)
      bfv[ni] = __builtin_bit_cast(bf16x8, *(const u16x8*)&Bs[cur][boff[ni]]);
    #pragma unroll
    for (int mi = 0; mi < 4; ++mi)
      #pragma unroll
      for (int ni = 0; ni < 4; ++ni)
        acc[mi][ni] = __builtin_amdgcn_mfma_f32_16x16x32_bf16(af[mi], bfv[ni], acc[mi][ni], 0, 0, 0);
    __syncthreads();
    cur ^= 1;
  }

  const int cq = w >> 1;
  float bv[4], sc[4], bb[4];
  #pragma unroll
  for (int ni = 0; ni < 4; ++ni){
    int col = cq * 64 + ni * 16 + fr;
    bv[ni] = bias[col]; sc[ni] = lns[col]; bb[ni] = lnb[col];
  }
  #pragma unroll
  for (int mi = 0; mi < 4; ++mi){
    #pragma unroll
    for (int i = 0; i < 4; ++i){
      float s1 = 0.f, s2 = 0.f;
      #pragma unroll
      for (int ni = 0; ni < 4; ++ni){
        float v = acc[mi][ni][i] + bv[ni];
        s1 += v; s2 += v * v;
      }
      #pragma unroll
      for (int off = 1; off < 16; off <<= 1){
        s1 += __shfl_xor(s1, off);
        s2 += __shfl_xor(s2, off);
      }
      if (fr == 0){
        int r = (w & 1) * 64 + mi * 16 + fq * 4 + i;
        rsum[r][cq] = s1; rsq[r][cq] = s2;
      }
    }
  }
  __syncthreads();
  #pragma unroll
  for (int mi = 0; mi < 4; ++mi){
    #pragma unroll
    for (int i = 0; i < 4; ++i){
      int r = (w & 1) * 64 + mi * 16 + fq * 4 + i;
      float S1 = rsum[r][0] + rsum[r][1] + rsum[r][2] + rsum[r][3];
      float S2 = rsq[r][0] + rsq[r][1] + rsq[r][2] + rsq[r][3];
      float mu  = S1 * (1.f / 256.f);
      float var = S2 * (1.f / 256.f) - mu * mu;
      float rs  = rsqrtf(var + 1e-5f);
      int row = row0 + r;
      if (row < M){
        #pragma unroll
        for (int ni = 0; ni < 4; ++ni){
          int col = cq * 64 + ni * 16 + fr;
          float nv = (acc[mi][ni][i] + bv[ni] - mu) * rs * sc[ni] + bb[ni];
          out[(size_t)row * 256 + col] = f2bf(nv * sigm(nv));
        }
      }
    }
  }
}

// --------------------- Wigner forward (MFMA, permuted) ---------------------
__global__ __launch_bounds__(256) void k_wig_fwd(
    const u16* __restrict__ xT, const int* __restrict__ eidx,
    const float* __restrict__ wig, const u16* __restrict__ xrad,
    u16* __restrict__ msgS, const int* __restrict__ perm, int e0)
{
  __shared__ u16 WL[32 * 64];
  int el = blockIdx.x, tid = threadIdx.x;
  int eg = perm[e0 + el];
  int lane = tid & 63, w = tid >> 6;

  const float* wp = wig + (size_t)eg * 1421;
  for (int idx = tid; idx < 2048; idx += 256){
    int m = idx >> 6, k = idx & 63;
    float v = (m < 29 && k < 49) ? wp[m * 49 + k] : 0.f;
    WL[m * 64 + ((((k >> 3) ^ (m & 7))) << 3) + (k & 7)] = f2bf(v);
  }

  const int fr = lane & 15, fq = lane >> 4;
  const int colbase = w * 64;
  int node = eidx[((w >> 1) ? E_NUM : 0) + eg];
  const u16* xb = xT + (size_t)node * 8192;
  bf16x8 bfv[4][2];
  #pragma unroll
  for (int ct = 0; ct < 4; ++ct)
    #pragma unroll
    for (int ks = 0; ks < 2; ++ks){
      int cc = ((w & 1) * 64) + ct * 16 + fr;       // within-node column
      bfv[ct][ks] = __builtin_bit_cast(bf16x8,
          *(const u16x8*)(xb + cc * 64 + (ks * 4 + fq) * 8));
    }
  __syncthreads();

  bf16x8 af[2][2];
  #pragma unroll
  for (int mt = 0; mt < 2; ++mt)
    #pragma unroll
    for (int ks = 0; ks < 2; ++ks){
      int m = mt * 16 + fr;
      int g = ks * 4 + fq;
      af[mt][ks] = __builtin_bit_cast(bf16x8,
          *(const u16x8*)&WL[m * 64 + ((g ^ (m & 7)) << 3)]);
    }
  f32x4 acc[2][4];
  #pragma unroll
  for (int mt = 0; mt < 2; ++mt)
    #pragma unroll
    for (int ct = 0; ct < 4; ++ct) acc[mt][ct] = (f32x4){0.f,0.f,0.f,0.f};
  #pragma unroll
  for (int mt = 0; mt < 2; ++mt)
    #pragma unroll
    for (int ct = 0; ct < 4; ++ct)
      #pragma unroll
      for (int ks = 0; ks < 2; ++ks)
        acc[mt][ct] = __builtin_amdgcn_mfma_f32_16x16x32_bf16(
            af[mt][ks], bfv[ct][ks], acc[mt][ct], 0, 0, 0);

  const u16* xr = xrad + (size_t)el * 4608;
  u16* o = msgS + (size_t)el * 7424;
  #pragma unroll
  for (int mt = 0; mt < 2; ++mt)
    #pragma unroll
    for (int ct = 0; ct < 4; ++ct){
      int col = colbase + ct * 16 + fr;
      #pragma unroll
      for (int r = 0; r < 4; ++r){
        int m = mt * 16 + fq * 4 + r;
        if (m < 29){
          int rr = (m < 13) ? m : (m < 24 ? m - 6 : m - 11);
          o[m * 256 + col] = f2bf(acc[mt][ct][r] * bf2f(xr[rr * 256 + col]));
        }
      }
    }
}

// -------------------- gate + recombine (conv1, u16x8) ----------------------
__global__ __launch_bounds__(256) void k_gate(
    const u16* __restrict__ c1m0, const u16* __restrict__ y10, const u16* __restrict__ y11,
    const u16* __restrict__ y20, const u16* __restrict__ y21, u16* __restrict__ msg2)
{
  int e = blockIdx.x, t = threadIdx.x;
  __shared__ float g[768];
  const u16* gp = c1m0 + (size_t)e * 1664;
  if (t < 96){
    u16x8 v = *(const u16x8*)(gp + t * 8);
    #pragma unroll
    for (int i = 0; i < 8; ++i) g[t * 8 + i] = sigm(bf2f(v[i]));
  }
  __syncthreads();
  const u16* x0 = gp + 768;
  const u16* a0 = y10 + (size_t)e * 1536;
  const u16* a1 = y11 + (size_t)e * 1536;
  const u16* b0 = y20 + (size_t)e * 1280;
  const u16* b1 = y21 + (size_t)e * 1280;
  u16* o = msg2 + (size_t)e * 3712;
  const int grp = (t & 15) * 8;
  for (int r = t >> 4; r < 29; r += 16){
    u16x8 outv;
    if (r == 0){
      u16x8 v = *(const u16x8*)(x0 + grp);
      #pragma unroll
      for (int i = 0; i < 8; ++i){ float f = bf2f(v[i]); outv[i] = f2bf(f * sigm(f)); }
    } else if (r < 7){
      u16x8 v = *(const u16x8*)(x0 + r * 128 + grp);
      #pragma unroll
      for (int i = 0; i < 8; ++i)
        outv[i] = f2bf(bf2f(v[i]) * g[(r - 1) * 128 + grp + i]);
    } else if (r < 19){
      int k = (r < 13) ? r - 7 : r - 13;
      u16x8 va = *(const u16x8*)(a0 + ((r < 13) ? k * 128 : 768 + k * 128) + grp);
      u16x8 vb = *(const u16x8*)(a1 + ((r < 13) ? 768 + k * 128 : k * 128) + grp);
      #pragma unroll
      for (int i = 0; i < 8; ++i){
        float fa = bf2f(va[i]), fb = bf2f(vb[i]);
        float val = (r < 13) ? (fa - fb) : (fb + fa);
        outv[i] = f2bf(val * g[k * 128 + grp + i]);
      }
    } else {
      int k = (r < 24) ? r - 19 : r - 24;
      u16x8 va = *(const u16x8*)(b0 + ((r < 24) ? k * 128 : 640 + k * 128) + grp);
      u16x8 vb = *(const u16x8*)(b1 + ((r < 24) ? 640 + k * 128 : k * 128) + grp);
      #pragma unroll
      for (int i = 0; i < 8; ++i){
        float fa = bf2f(va[i]), fb = bf2f(vb[i]);
        float val = (r < 24) ? (fa - fb) : (fb + fa);
        outv[i] = f2bf(val * g[(1 + k) * 128 + grp + i]);
      }
    }
    *(u16x8*)(o + r * 128 + grp) = outv;
  }
}

// -------- recombine2 + envelope -> msg3T (c,m); LDS-staged u16x8 reads -----
__global__ __launch_bounds__(128) void k_recomb2(
    const u16* __restrict__ m3x0, const u16* __restrict__ z10, const u16* __restrict__ z11,
    const u16* __restrict__ z20, const u16* __restrict__ z21, const float* __restrict__ env,
    u16* __restrict__ msg3T, const int* __restrict__ perm, int e0)
{
  __shared__ u16 s[6528];
  int e = blockIdx.x, c = threadIdx.x;
  {
    const u16* px0 = m3x0 + (size_t)e * 896;
    const u16* pa0 = z10 + (size_t)e * 1536;
    const u16* pa1 = z11 + (size_t)e * 1536;
    const u16* pb0 = z20 + (size_t)e * 1280;
    const u16* pb1 = z21 + (size_t)e * 1280;
    for (int v = c; v < 112; v += 128) *(u16x8*)(&s[v * 8])        = *(const u16x8*)(px0 + v * 8);
    for (int v = c; v < 192; v += 128) *(u16x8*)(&s[896 + v * 8])  = *(const u16x8*)(pa0 + v * 8);
    for (int v = c; v < 192; v += 128) *(u16x8*)(&s[2432 + v * 8]) = *(const u16x8*)(pa1 + v * 8);
    for (int v = c; v < 160; v += 128) *(u16x8*)(&s[3968 + v * 8]) = *(const u16x8*)(pb0 + v * 8);
    for (int v = c; v < 160; v += 128) *(u16x8*)(&s[5248 + v * 8]) = *(const u16x8*)(pb1 + v * 8);
  }
  __syncthreads();
  float ev = env[perm[e0 + e]];
  const u16* x0 = s;
  const u16* a0 = s + 896;
  const u16* a1 = s + 2432;
  const u16* b0 = s + 3968;
  const u16* b1 = s + 5248;
  u16 v[32];
  #pragma unroll
  for (int r = 0; r < 7; ++r) v[r] = f2bf(bf2f(x0[r * 128 + c]) * ev);
  #pragma unroll
  for (int k = 0; k < 6; ++k){
    float orr = bf2f(a0[k * 128 + c]) - bf2f(a1[768 + k * 128 + c]);
    float oii = bf2f(a1[k * 128 + c]) + bf2f(a0[768 + k * 128 + c]);
    v[7 + k]  = f2bf(orr * ev);
    v[13 + k] = f2bf(oii * ev);
  }
  #pragma unroll
  for (int k = 0; k < 5; ++k){
    float orr = bf2f(b0[k * 128 + c]) - bf2f(b1[640 + k * 128 + c]);
    float oii = bf2f(b1[k * 128 + c]) + bf2f(b0[640 + k * 128 + c]);
    v[19 + k] = f2bf(orr * ev);
    v[24 + k] = f2bf(oii * ev);
  }
  v[29] = 0; v[30] = 0; v[31] = 0;
  u16* o = msg3T + (size_t)e * 4096 + c * 32;
  #pragma unroll
  for (int q = 0; q < 4; ++q)
    *(u16x8*)(o + q * 8) = *(const u16x8*)(&v[q * 8]);
}

// --------- Wigner inverse (MFMA, node-indexed run-gather, W dbuf) ----------
__global__ __launch_bounds__(256) void k_wig_inv(
    const u16* __restrict__ msg3T, const float* __restrict__ winv,
    const int* __restrict__ cnt, const int* __restrict__ soff,
    float* __restrict__ out, const int* __restrict__ perm, int e0, int cm)
{
  __shared__ u16 WV[2][2048];
  int d = blockIdx.x, tid = threadIdx.x;
  int cn = cnt[d];
  if (cn == 0) return;
  int runEnd = soff[d];           // post-scatter soff = run end
  int runStart = runEnd - cn;
  int start = runStart < e0 ? e0 : runStart;
  int end   = runEnd > e0 + cm ? e0 + cm : runEnd;
  if (start >= end) return;
  bool atom = (start != runStart) || (end != runEnd);

  int lane = tid & 63, w = tid >> 6;
  const int fr = lane & 15, fq = lane >> 4;
  const int jr = w * 16 + fr;

  auto stageW = [&](int buf, int pe){
    const float* wp = winv + (size_t)pe * 1421;
    for (int idx = tid; idx < 2048; idx += 256){
      int j = idx >> 5, m = idx & 31;
      float v = (j < 49 && m < 29) ? wp[j * 29 + m] : 0.f;
      WV[buf][j * 32 + (((m >> 3) ^ (j & 3)) << 3) + (m & 7)] = f2bf(v);
    }
  };

  f32x4 acc[8];
  #pragma unroll
  for (int ct = 0; ct < 8; ++ct) acc[ct] = (f32x4){0.f,0.f,0.f,0.f};

  stageW(0, perm[start]);
  __syncthreads();
  int b = 0;
  for (int t = start; t < end; ++t){
    if (t + 1 < end) stageW(b ^ 1, perm[t + 1]);
    bf16x8 a = __builtin_bit_cast(bf16x8,
        *(const u16x8*)&WV[b][jr * 32 + ((fq ^ (jr & 3)) << 3)]);
    const u16* bp = msg3T + (size_t)(t - e0) * 4096;
    #pragma unroll
    for (int ct = 0; ct < 8; ++ct){
      bf16x8 bo = __builtin_bit_cast(bf16x8,
          *(const u16x8*)(bp + (ct * 16 + fr) * 32 + fq * 8));
      acc[ct] = __builtin_amdgcn_mfma_f32_16x16x32_bf16(a, bo, acc[ct], 0, 0, 0);
    }
    __syncthreads();
    b ^= 1;
  }

  float* op = out + (size_t)d * 6272;
  if (atom){
    #pragma unroll
    for (int ct = 0; ct < 8; ++ct){
      int c = ct * 16 + fr;
      #pragma unroll
      for (int r = 0; r < 4; ++r){
        int j = w * 16 + fq * 4 + r;
        if (j < 49) atomicAdd(op + j * 128 + c, acc[ct][r]);
      }
    }
  } else {
    #pragma unroll
    for (int ct = 0; ct < 8; ++ct){
      int c = ct * 16 + fr;
      #pragma unroll
      for (int r = 0; r < 4; ++r){
        int j = w * 16 + fq * 4 + r;
        if (j < 49) op[j * 128 + c] = acc[ct][r];
      }
    }
  }
}

// ---------------------------------------------------------------------------
extern "C" void kernel_launch(void* const* d_in, const int* in_sizes, int n_in,
                              void* d_out, int out_size, void* d_ws, size_t ws_size,
                              hipStream_t stream)
{
  (void)in_sizes; (void)n_in;
  const float* x       = (const float*)d_in[0];
  const float* x_edge  = (const float*)d_in[1];
  const int*   eidx    = (const int*)d_in[3];
  const float* wig     = (const float*)d_in[4];
  const float* wig_inv = (const float*)d_in[5];
  const float* env     = (const float*)d_in[6];
  const float* rad_w0  = (const float*)d_in[7];
  const float* rad_b0  = (const float*)d_in[8];
  const float* ln0_s   = (const float*)d_in[9];
  const float* ln0_b   = (const float*)d_in[10];
  const float* rad_w1  = (const float*)d_in[11];
  const float* rad_b1  = (const float*)d_in[12];
  const float* ln1_s   = (const float*)d_in[13];
  const float* ln1_b   = (const float*)d_in[14];
  const float* rad_w2  = (const float*)d_in[15];
  const float* rad_b2  = (const float*)d_in[16];
  const float* c1w0    = (const float*)d_in[17];
  const float* c1b0    = (const float*)d_in[18];
  const float* c1w1    = (const float*)d_in[19];
  const float* c1w2    = (const float*)d_in[20];
  const float* c2w0    = (const float*)d_in[21];
  const float* c2b0    = (const float*)d_in[22];
  const float* c2w1    = (const float*)d_in[23];
  const float* c2w2    = (const float*)d_in[24];
  float* out = (float*)d_out;

  char* base = (char*)d_ws;
  size_t off = 0;
  auto alloc = [&](size_t bytes) -> char* {
    off = (off + 255) & ~(size_t)255;
    char* r = base + off;
    off += bytes;
    return r;
  };

  // ---- fixed area: bf16 weights (~22.2 MB) + xT (78 MB) + sort arrays ----
  u16* wtR0  = (u16*)alloc((size_t)256  * 128  * 2);
  u16* wtR1  = (u16*)alloc((size_t)256  * 256  * 2);
  u16* wtR2  = (u16*)alloc((size_t)4608 * 256  * 2);
  u16* wtC10 = (u16*)alloc((size_t)1664 * 1792 * 2);
  u16* wtC11 = (u16*)alloc((size_t)1536 * 1536 * 2);
  u16* wtC12 = (u16*)alloc((size_t)1280 * 1280 * 2);
  u16* wtC20 = (u16*)alloc((size_t)896  * 896  * 2);
  u16* wtC21 = (u16*)alloc((size_t)1536 * 768  * 2);
  u16* wtC22 = (u16*)alloc((size_t)1280 * 640  * 2);
  u16* xT    = (u16*)alloc((size_t)NN * 8192 * 2);
  int* cnt   = (int*)alloc(NN * 4);
  int* soff  = (int*)alloc(NN * 4);
  int* perm  = (int*)alloc(E_NUM * 4);

  // ---- chunk size from remaining workspace (40,960 B per edge kept) ----
  size_t fixed_end = (off + 65536) & ~(size_t)65535;
  size_t avail = (ws_size > fixed_end + (1u << 20)) ? (ws_size - fixed_end - (1u << 20)) : 0;
  long CH0 = (long)(avail / 40960);
  if (CH0 > E_NUM) CH0 = E_NUM;
  if (CH0 < 64) CH0 = 64;
  int nch = (int)((E_NUM + CH0 - 1) / CH0);
  int CH = (E_NUM + nch - 1) / nch;          // equalized chunks
  if (CH > CH0) CH = (int)CH0;

  off = fixed_end;
  const size_t C = (size_t)CH;
  u16*   xe   = (u16*)alloc(C * 128 * 2);
  u16*   h0   = (u16*)alloc(C * 256 * 2);
  u16*   h1   = (u16*)alloc(C * 256 * 2);
  u16* region1 = (u16*)alloc(C * 4608 * 2);   // xrad -> msg2
  u16* region2 = (u16*)alloc(C * 7424 * 2);   // msgS -> conv2 outs
  u16* region3 = (u16*)alloc(C * 7296 * 2);   // conv1 outs -> msg3T
  u16* xrad = region1;
  u16* msg2 = region1;
  u16* msgS = region2;
  u16* m3x0 = region2;                 // (C,896)
  u16* z10  = region2 + C * 896;       // (C,1536)
  u16* z11  = region2 + C * 2432;      // (C,1536)
  u16* z20  = region2 + C * 3968;      // (C,1280)
  u16* z21  = region2 + C * 5248;      // (C,1280)
  u16* c1m0b = region3;                // (C,1664)
  u16* y10   = region3 + C * 1664;     // (C,1536)
  u16* y11   = region3 + C * 3200;     // (C,1536)
  u16* y20   = region3 + C * 4736;     // (C,1280)
  u16* y21   = region3 + C * 6016;     // (C,1280)
  u16* msg3T = region3;                // (C,4096) transposed (c,m)

  hipMemsetAsync(d_out, 0, (size_t)out_size * sizeof(float), stream);
  hipMemsetAsync(cnt, 0, NN * 4, stream);

  // dst counting sort -> perm ; x transpose
  k_hist<<<(E_NUM + 255) / 256, 256, 0, stream>>>(eidx, cnt);
  k_scan<<<1, 256, 0, stream>>>(cnt, soff);
  k_scatter<<<(E_NUM + 255) / 256, 256, 0, stream>>>(eidx, soff, perm);
  k_xpose<<<NN, 256, 0, stream>>>(x, xT);

  auto tw = [&](const float* in, u16* o, int K, int N){
    k_transpose_w<<<dim3(N / 32, K / 32), 256, 0, stream>>>(in, o, K, N);
  };
  tw(rad_w0, wtR0, 128, 256);
  tw(rad_w1, wtR1, 256, 256);
  tw(rad_w2, wtR2, 256, 4608);
  tw(c1w0, wtC10, 1792, 1664);
  tw(c1w1, wtC11, 1536, 1536);
  tw(c1w2, wtC12, 1280, 1280);
  tw(c2w0, wtC20, 896, 896);
  tw(c2w1, wtC21, 768, 1536);
  tw(c2w2, wtC22, 640, 1280);

  for (int e0 = 0; e0 < E_NUM; e0 += CH){
    int cm = E_NUM - e0 < CH ? E_NUM - e0 : CH;
    int mb = (cm + 127) / 128;

    k_gather_xe<<<cm, 128, 0, stream>>>(x_edge, perm, xe, e0);

    // radial MLP: 2 fused gemm+LN+SiLU + final wide gemm
    k_gemm_ln<<<mb, 512, 0, stream>>>(xe, 128, wtR0, rad_b0, ln0_s, ln0_b, h0, cm, 128);
    k_gemm_ln<<<mb, 512, 0, stream>>>(h0, 256, wtR1, rad_b1, ln1_s, ln1_b, h1, cm, 256);
    k_gemm_bt<<<dim3(4608 / 128, mb), 256, 0, stream>>>(
        h1, 256, wtR2, rad_b2, nullptr, xrad, 4608, cm, 4608, 256);

    // wigner forward (MFMA, B-frags from global xT)
    k_wig_fwd<<<cm, 256, 0, stream>>>(xT, eidx, wig, xrad, msgS, perm, e0);

    // conv1: one segmented launch
    {
      Seg5 g;
      int b = 0;
      auto mk = [&](const u16* A, const u16* B, u16* Cb, const float* bias,
                    int N, int K) -> Seg {
        Seg s{A, B, Cb, bias, cm, N, K, 7424, b};
        b += (N >> 7) * mb;
        return s;
      };
      g.s[0] = mk(msgS,        wtC10, c1m0b, c1b0,   1664, 1792);
      g.s[1] = mk(msgS + 1792, wtC11, y10,   nullptr, 1536, 1536);
      g.s[2] = mk(msgS + 3328, wtC11, y11,   nullptr, 1536, 1536);
      g.s[3] = mk(msgS + 4864, wtC12, y20,   nullptr, 1280, 1280);
      g.s[4] = mk(msgS + 6144, wtC12, y21,   nullptr, 1280, 1280);
      g.nwg = b;
      k_gemm_seg<<<b, 256, 0, stream>>>(g);
    }

    k_gate<<<cm, 256, 0, stream>>>(c1m0b, y10, y11, y20, y21, msg2);

    // conv2: one segmented launch
    {
      Seg5 g;
      int b = 0;
      auto mk = [&](const u16* A, const u16* B, u16* Cb, const float* bias,
                    int N, int K) -> Seg {
        Seg s{A, B, Cb, bias, cm, N, K, 3712, b};
        b += (N >> 7) * mb;
        return s;
      };
      g.s[0] = mk(msg2,        wtC20, m3x0, c2b0,   896,  896);
      g.s[1] = mk(msg2 + 896,  wtC21, z10,  nullptr, 1536, 768);
      g.s[2] = mk(msg2 + 1664, wtC21, z11,  nullptr, 1536, 768);
      g.s[3] = mk(msg2 + 2432, wtC22, z20,  nullptr, 1280, 640);
      g.s[4] = mk(msg2 + 3072, wtC22, z21,  nullptr, 1280, 640);
      g.nwg = b;
      k_gemm_seg<<<b, 256, 0, stream>>>(g);
    }

    k_recomb2<<<cm, 128, 0, stream>>>(m3x0, z10, z11, z20, z21, env, msg3T, perm, e0);

    // wigner inverse: node-indexed run-gather, W dbuf
    k_wig_inv<<<NN, 256, 0, stream>>>(msg3T, wig_inv, cnt, soff, out, perm, e0, cm);
  }
}

// Round 15
// 2304.086 us; speedup vs baseline: 1.0785x; 1.0062x over previous
//
#include <hip/hip_runtime.h>
#include <stdint.h>

// ---------------------------------------------------------------------------
// Edgewise (eSCN SO(2) conv block), MI355X gfx950.
// Round 15: conv/radial GEMM core -> 128x256 tile, 8 waves, 512 threads
// (generalized from the verified k_gemm_ln shape): halves A-tile traffic,
// 2x MFMA per barrier, 24 waves/CU. conv m0 segments padded to N%256==0
// (c1m0 1664->1792, c2m0 896->1024; zeroed pad rows, guarded bias).
// 2-buf __syncthreads loop (counted-vmcnt was null in r14).
// ---------------------------------------------------------------------------

#define E_NUM   20000
#define NN      5000

typedef uint16_t u16;
typedef __bf16  bf16x8 __attribute__((ext_vector_type(8)));
typedef float   f32x4  __attribute__((ext_vector_type(4)));
typedef uint16_t u16x8 __attribute__((ext_vector_type(8)));

__device__ __forceinline__ float bf2f(u16 h){
  uint32_t u = ((uint32_t)h) << 16;
  return __builtin_bit_cast(float, u);
}
__device__ __forceinline__ u16 f2bf(float f){
  uint32_t u = __builtin_bit_cast(uint32_t, f);
  u += 0x7fffu + ((u >> 16) & 1u);
  return (u16)(u >> 16);
}
__device__ __forceinline__ float sigm(float x){ return 1.f / (1.f + __expf(-x)); }

__device__ __forceinline__ void gload16(const void* g, void* l){
  __builtin_amdgcn_global_load_lds(
      (const __attribute__((address_space(1))) void*)g,
      (__attribute__((address_space(3))) void*)l, 16, 0, 0);
}

// bijective XCD swizzle (m204)
__device__ __forceinline__ int swz8(int orig, int nwg){
  int q = nwg >> 3, r = nwg & 7;
  int x = orig & 7, p = orig >> 3;
  int base = (x < r) ? x * (q + 1) : r * (q + 1) + (x - r) * q;
  return base + p;
}

// ----------------------- dst counting sort ---------------------------------
__global__ void k_hist(const int* __restrict__ eidx, int* __restrict__ cnt){
  int e = blockIdx.x * 256 + threadIdx.x;
  if (e < E_NUM) atomicAdd(&cnt[eidx[E_NUM + e]], 1);
}
__global__ __launch_bounds__(256) void k_scan(const int* __restrict__ cnt,
                                              int* __restrict__ off){
  __shared__ int part[256];
  int t = threadIdx.x;
  int s = 0;
  #pragma unroll
  for (int i = 0; i < 20; ++i){
    int idx = t * 20 + i;
    if (idx < NN) s += cnt[idx];
  }
  part[t] = s;
  __syncthreads();
  if (t == 0){
    int run = 0;
    for (int i = 0; i < 256; ++i){ int v = part[i]; part[i] = run; run += v; }
  }
  __syncthreads();
  int run = part[t];
  #pragma unroll
  for (int i = 0; i < 20; ++i){
    int idx = t * 20 + i;
    if (idx < NN){ off[idx] = run; run += cnt[idx]; }
  }
}
__global__ void k_scatter(const int* __restrict__ eidx, int* __restrict__ off,
                          int* __restrict__ perm){
  int e = blockIdx.x * 256 + threadIdx.x;
  if (e < E_NUM){
    int pos = atomicAdd(&off[eidx[E_NUM + e]], 1);
    perm[pos] = e;
  }
}

// --------------------------- weight transpose ------------------------------
__global__ void k_transpose_w(const float* __restrict__ in, u16* __restrict__ out,
                              int K, int N){
  __shared__ float t[32][33];
  int nb = blockIdx.x * 32, kb = blockIdx.y * 32;
  int tx = threadIdx.x & 31, ty = threadIdx.x >> 5;   // 32x8
  for (int i = ty; i < 32; i += 8)
    t[i][tx] = in[(size_t)(kb + i) * N + (nb + tx)];
  __syncthreads();
  for (int i = ty; i < 32; i += 8)
    out[(size_t)(nb + i) * K + (kb + tx)] = f2bf(t[tx][i]);
}

// zero-fill helper (pads weight buffers)
__global__ void k_zero16(u16* __restrict__ p, int n){
  int i = blockIdx.x * 256 + threadIdx.x;
  int stride = gridDim.x * 256;
  for (; i < n; i += stride) p[i] = 0;
}

// ------------- x -> xT bf16, [node][c=128][k=64 padded], once --------------
__global__ __launch_bounds__(256) void k_xpose(const float* __restrict__ x,
                                               u16* __restrict__ xT){
  __shared__ float t[6272];
  int n = blockIdx.x, tid = threadIdx.x;
  const float* xp = x + (size_t)n * 6272;
  for (int i = tid; i < 6272; i += 256) t[i] = xp[i];
  __syncthreads();
  int c = tid >> 1;
  int kh = (tid & 1) * 32;
  u16* o = xT + (size_t)n * 8192 + c * 64 + kh;
  #pragma unroll
  for (int q = 0; q < 4; ++q){
    u16x8 h;
    #pragma unroll
    for (int i = 0; i < 8; ++i){
      int k = kh + q * 8 + i;
      h[i] = (k < 49) ? f2bf(t[k * 128 + c]) : (u16)0;
    }
    *(u16x8*)(o + q * 8) = h;
  }
}

// gather x_edge rows in permuted order -> bf16
__global__ void k_gather_xe(const float* __restrict__ x_edge,
                            const int* __restrict__ perm,
                            u16* __restrict__ xe, int e0){
  int el = blockIdx.x, c = threadIdx.x;
  int pe = perm[e0 + el];
  xe[(size_t)el * 128 + c] = f2bf(x_edge[(size_t)pe * 128 + c]);
}

// ---------------- GEMM core: 128x256 tile, 8 waves, 512 thr ----------------
// Wave w: rows (w&1)*64, cols (w>>1)*64 (same decomposition as k_gemm_ln).
struct Seg {
  const u16* A; const u16* B; u16* C; const float* bias;
  int M, N, K, lda, blk0, Nb;
};
struct Seg5 { Seg s[5]; int nwg; };

__device__ __forceinline__ void gemm_tile256(
    const u16* __restrict__ A, int lda, const u16* __restrict__ B,
    const float* __restrict__ bias, int Nb, u16* __restrict__ Cb,
    float* __restrict__ Cf, int ldc, int M, int K,
    int bm, int bn, u16* As /*2*4096*/, u16* Bs /*2*8192*/)
{
  const int tid = threadIdx.x, lane = tid & 63, w = tid >> 6;
  const int fr = lane & 15, fq = lane >> 4;
  const int row0 = bm * 128, col0 = bn * 256;

  // staging (identical pattern to verified k_gemm_ln)
  const int lr = lane >> 2, lg = lane & 3;
  int rA = w * 16 + lr;
  int gA = lg ^ ((rA >> 1) & 3);
  int grA = row0 + rA; if (grA > M - 1) grA = M - 1;
  const u16* aS = A + (size_t)grA * lda + gA * 8;
  int rB0 = w * 32 + lr, rB1 = rB0 + 16;
  int gB0 = lg ^ ((rB0 >> 1) & 3), gB1 = lg ^ ((rB1 >> 1) & 3);
  const u16* bS0 = B + (size_t)(col0 + rB0) * K + gB0 * 8;
  const u16* bS1 = B + (size_t)(col0 + rB1) * K + gB1 * 8;
  const int dA  = (w * 16) * 32;
  const int dB0 = (w * 32) * 32;
  const int dB1 = (w * 32 + 16) * 32;

  int aoff[4], boff[4];
  #pragma unroll
  for (int mi = 0; mi < 4; ++mi){
    int r = (w & 1) * 64 + mi * 16 + fr;
    aoff[mi] = r * 32 + (fq ^ ((r >> 1) & 3)) * 8;
  }
  #pragma unroll
  for (int ni = 0; ni < 4; ++ni){
    int cc = (w >> 1) * 64 + ni * 16 + fr;
    boff[ni] = cc * 32 + (fq ^ ((cc >> 1) & 3)) * 8;
  }

  f32x4 acc[4][4];
  #pragma unroll
  for (int i = 0; i < 4; ++i)
    #pragma unroll
    for (int j = 0; j < 4; ++j) acc[i][j] = (f32x4){0.f, 0.f, 0.f, 0.f};

  auto stage = [&](int buf, int k0){
    gload16(aS + k0, &As[buf * 4096 + dA]);
    gload16(bS0 + k0, &Bs[buf * 8192 + dB0]);
    gload16(bS1 + k0, &Bs[buf * 8192 + dB1]);
  };

  stage(0, 0);
  __syncthreads();
  int cur = 0;
  for (int k0 = 0; k0 < K; k0 += 32){
    if (k0 + 32 < K) stage(cur ^ 1, k0 + 32);
    bf16x8 af[4], bfv[4];
    #pragma unroll
    for (int mi = 0; mi < 4; ++mi)
      af[mi] = __builtin_bit_cast(bf16x8, *(const u16x8*)&As[cur * 4096 + aoff[mi]]);
    #pragma unroll
    for (int ni = 0; ni < 4; ++ni)
      bfv[ni] = __builtin_bit_cast(bf16x8, *(const u16x8*)&Bs[cur * 8192 + boff[ni]]);
    #pragma unroll
    for (int mi = 0; mi < 4; ++mi)
      #pragma unroll
      for (int ni = 0; ni < 4; ++ni)
        acc[mi][ni] = __builtin_amdgcn_mfma_f32_16x16x32_bf16(af[mi], bfv[ni], acc[mi][ni], 0, 0, 0);
    __syncthreads();
    cur ^= 1;
  }

  #pragma unroll
  for (int ni = 0; ni < 4; ++ni){
    int col = col0 + (w >> 1) * 64 + ni * 16 + fr;
    float bv = (bias && col < Nb) ? bias[col] : 0.f;
    #pragma unroll
    for (int mi = 0; mi < 4; ++mi){
      #pragma unroll
      for (int i = 0; i < 4; ++i){
        int row = row0 + (w & 1) * 64 + mi * 16 + fq * 4 + i;
        if (row < M){
          float v = acc[mi][ni][i] + bv;
          if (Cb) Cb[(size_t)row * ldc + col] = f2bf(v);
          else    Cf[(size_t)row * ldc + col] = v;
        }
      }
    }
  }
}

// plain wide GEMM (radial w2); N % 256 == 0, ldc == N
__global__ __launch_bounds__(512) void k_gemm_bt256(
    const u16* __restrict__ A, int lda, const u16* __restrict__ B,
    const float* __restrict__ bias, int Nb, float* __restrict__ Cf,
    u16* __restrict__ Cb, int ldc, int M, int K)
{
  __shared__ u16 As[2 * 4096];
  __shared__ u16 Bs[2 * 8192];
  gemm_tile256(A, lda, B, bias, Nb, Cb, Cf, ldc, M, K,
               blockIdx.y, blockIdx.x, As, Bs);
}

// segmented GEMM: 5 independent GEMMs (N % 256 == 0) in one launch
__global__ __launch_bounds__(512) void k_gemm_seg(Seg5 g)
{
  __shared__ u16 As[2 * 4096];
  __shared__ u16 Bs[2 * 8192];
  int wgid = swz8(blockIdx.x, g.nwg);
  Seg sg = g.s[4];
  if (wgid < g.s[4].blk0) sg = g.s[3];
  if (wgid < g.s[3].blk0) sg = g.s[2];
  if (wgid < g.s[2].blk0) sg = g.s[1];
  if (wgid < g.s[1].blk0) sg = g.s[0];
  int local = wgid - sg.blk0;
  int nbx = sg.N >> 8;
  int bn = local % nbx;
  int bm = local / nbx;
  gemm_tile256(sg.A, sg.lda, sg.B, sg.bias, sg.Nb, sg.C, nullptr, sg.N,
               sg.M, sg.K, bm, bn, As, Bs);
}

// ------------------ fused GEMM(N=256) + LayerNorm + SiLU -------------------
__global__ __launch_bounds__(512) void k_gemm_ln(
    const u16* __restrict__ A, int lda, const u16* __restrict__ B /*(256,K)*/,
    const float* __restrict__ bias, const float* __restrict__ lns,
    const float* __restrict__ lnb, u16* __restrict__ out, int M, int K)
{
  __shared__ u16 As[2][4096];    // 128 x 32
  __shared__ u16 Bs[2][8192];    // 256 x 32
  __shared__ float rsum[128][4], rsq[128][4];
  const int tid = threadIdx.x, lane = tid & 63, w = tid >> 6;
  const int fr = lane & 15, fq = lane >> 4;
  const int bm = blockIdx.x, row0 = bm * 128;

  const int lr = lane >> 2, lg = lane & 3;
  int rA = w * 16 + lr;
  int gA = lg ^ ((rA >> 1) & 3);
  int grA = row0 + rA; if (grA > M - 1) grA = M - 1;
  const u16* aS = A + (size_t)grA * lda + gA * 8;
  int rB0 = w * 32 + lr, rB1 = rB0 + 16;
  int gB0 = lg ^ ((rB0 >> 1) & 3), gB1 = lg ^ ((rB1 >> 1) & 3);
  const u16* bS0 = B + (size_t)rB0 * K + gB0 * 8;
  const u16* bS1 = B + (size_t)rB1 * K + gB1 * 8;
  const int dA  = (w * 16) * 32;
  const int dB0 = (w * 32) * 32;
  const int dB1 = (w * 32 + 16) * 32;

  int aoff[4], boff[4];
  #pragma unroll
  for (int mi = 0; mi < 4; ++mi){
    int r = (w & 1) * 64 + mi * 16 + fr;
    aoff[mi] = r * 32 + (fq ^ ((r >> 1) & 3)) * 8;
  }
  #pragma unroll
  for (int ni = 0; ni < 4; ++ni){
    int ccol = (w >> 1) * 64 + ni * 16 + fr;
    boff[ni] = ccol * 32 + (fq ^ ((ccol >> 1) & 3)) * 8;
  }

  f32x4 acc[4][4];
  #pragma unroll
  for (int i = 0; i < 4; ++i)
    #pragma unroll
    for (int j = 0; j < 4; ++j) acc[i][j] = (f32x4){0.f, 0.f, 0.f, 0.f};

  auto stage = [&](int buf, int k0){
    gload16(aS + k0, &As[buf][dA]);
    gload16(bS0 + k0, &Bs[buf][dB0]);
    gload16(bS1 + k0, &Bs[buf][dB1]);
  };

  stage(0, 0);
  __syncthreads();
  int cur = 0;
  for (int k0 = 0; k0 < K; k0 += 32){
    if (k0 + 32 < K) stage(cur ^ 1, k0 + 32);
    bf16x8 af[4], bfv[4];
    #pragma unroll
    for (int mi = 0; mi < 4; ++mi)
      af[mi] = __builtin_bit_cast(bf16x8, *(const u16x8*)&As[cur][aoff[mi]]);
    #pragma unroll
    for (int ni = 0; ni < 4; ++ni)
      bfv[ni] = __builtin_bit_cast(bf16x8, *(const u16x8*)&Bs[cur][boff[ni]]);
    #pragma unroll
    for (int mi = 0; mi < 4; ++mi)
      #pragma unroll
      for (int ni = 0; ni < 4; ++ni)
        acc[mi][ni] = __builtin_amdgcn_mfma_f32_16x16x32_bf16(af[mi], bfv[ni], acc[mi][ni], 0, 0, 0);
    __syncthreads();
    cur ^= 1;
  }

  const int cq = w >> 1;
  float bv[4], sc[4], bb[4];
  #pragma unroll
  for (int ni = 0; ni < 4; ++ni){
    int col = cq * 64 + ni * 16 + fr;
    bv[ni] = bias[col]; sc[ni] = lns[col]; bb[ni] = lnb[col];
  }
  #pragma unroll
  for (int mi = 0; mi < 4; ++mi){
    #pragma unroll
    for (int i = 0; i < 4; ++i){
      float s1 = 0.f, s2 = 0.f;
      #pragma unroll
      for (int ni = 0; ni < 4; ++ni){
        float v = acc[mi][ni][i] + bv[ni];
        s1 += v; s2 += v * v;
      }
      #pragma unroll
      for (int off = 1; off < 16; off <<= 1){
        s1 += __shfl_xor(s1, off);
        s2 += __shfl_xor(s2, off);
      }
      if (fr == 0){
        int r = (w & 1) * 64 + mi * 16 + fq * 4 + i;
        rsum[r][cq] = s1; rsq[r][cq] = s2;
      }
    }
  }
  __syncthreads();
  #pragma unroll
  for (int mi = 0; mi < 4; ++mi){
    #pragma unroll
    for (int i = 0; i < 4; ++i){
      int r = (w & 1) * 64 + mi * 16 + fq * 4 + i;
      float S1 = rsum[r][0] + rsum[r][1] + rsum[r][2] + rsum[r][3];
      float S2 = rsq[r][0] + rsq[r][1] + rsq[r][2] + rsq[r][3];
      float mu  = S1 * (1.f / 256.f);
      float var = S2 * (1.f / 256.f) - mu * mu;
      float rs  = rsqrtf(var + 1e-5f);
      int row = row0 + r;
      if (row < M){
        #pragma unroll
        for (int ni = 0; ni < 4; ++ni){
          int col = cq * 64 + ni * 16 + fr;
          float nv = (acc[mi][ni][i] + bv[ni] - mu) * rs * sc[ni] + bb[ni];
          out[(size_t)row * 256 + col] = f2bf(nv * sigm(nv));
        }
      }
    }
  }
}

// --------------------- Wigner forward (MFMA, permuted) ---------------------
__global__ __launch_bounds__(256) void k_wig_fwd(
    const u16* __restrict__ xT, const int* __restrict__ eidx,
    const float* __restrict__ wig, const u16* __restrict__ xrad,
    u16* __restrict__ msgS, const int* __restrict__ perm, int e0)
{
  __shared__ u16 WL[32 * 64];
  int el = blockIdx.x, tid = threadIdx.x;
  int eg = perm[e0 + el];
  int lane = tid & 63, w = tid >> 6;

  const float* wp = wig + (size_t)eg * 1421;
  for (int idx = tid; idx < 2048; idx += 256){
    int m = idx >> 6, k = idx & 63;
    float v = (m < 29 && k < 49) ? wp[m * 49 + k] : 0.f;
    WL[m * 64 + ((((k >> 3) ^ (m & 7))) << 3) + (k & 7)] = f2bf(v);
  }

  const int fr = lane & 15, fq = lane >> 4;
  const int colbase = w * 64;
  int node = eidx[((w >> 1) ? E_NUM : 0) + eg];
  const u16* xb = xT + (size_t)node * 8192;
  bf16x8 bfv[4][2];
  #pragma unroll
  for (int ct = 0; ct < 4; ++ct)
    #pragma unroll
    for (int ks = 0; ks < 2; ++ks){
      int cc = ((w & 1) * 64) + ct * 16 + fr;       // within-node column
      bfv[ct][ks] = __builtin_bit_cast(bf16x8,
          *(const u16x8*)(xb + cc * 64 + (ks * 4 + fq) * 8));
    }
  __syncthreads();

  bf16x8 af[2][2];
  #pragma unroll
  for (int mt = 0; mt < 2; ++mt)
    #pragma unroll
    for (int ks = 0; ks < 2; ++ks){
      int m = mt * 16 + fr;
      int g = ks * 4 + fq;
      af[mt][ks] = __builtin_bit_cast(bf16x8,
          *(const u16x8*)&WL[m * 64 + ((g ^ (m & 7)) << 3)]);
    }
  f32x4 acc[2][4];
  #pragma unroll
  for (int mt = 0; mt < 2; ++mt)
    #pragma unroll
    for (int ct = 0; ct < 4; ++ct) acc[mt][ct] = (f32x4){0.f,0.f,0.f,0.f};
  #pragma unroll
  for (int mt = 0; mt < 2; ++mt)
    #pragma unroll
    for (int ct = 0; ct < 4; ++ct)
      #pragma unroll
      for (int ks = 0; ks < 2; ++ks)
        acc[mt][ct] = __builtin_amdgcn_mfma_f32_16x16x32_bf16(
            af[mt][ks], bfv[ct][ks], acc[mt][ct], 0, 0, 0);

  const u16* xr = xrad + (size_t)el * 4608;
  u16* o = msgS + (size_t)el * 7424;
  #pragma unroll
  for (int mt = 0; mt < 2; ++mt)
    #pragma unroll
    for (int ct = 0; ct < 4; ++ct){
      int col = colbase + ct * 16 + fr;
      #pragma unroll
      for (int r = 0; r < 4; ++r){
        int m = mt * 16 + fq * 4 + r;
        if (m < 29){
          int rr = (m < 13) ? m : (m < 24 ? m - 6 : m - 11);
          o[m * 256 + col] = f2bf(acc[mt][ct][r] * bf2f(xr[rr * 256 + col]));
        }
      }
    }
}

// -------------------- gate + recombine (conv1, u16x8) ----------------------
// c1m0 rows have ldc 1792 (last 128 cols = pad).
__global__ __launch_bounds__(256) void k_gate(
    const u16* __restrict__ c1m0, const u16* __restrict__ y10, const u16* __restrict__ y11,
    const u16* __restrict__ y20, const u16* __restrict__ y21, u16* __restrict__ msg2)
{
  int e = blockIdx.x, t = threadIdx.x;
  __shared__ float g[768];
  const u16* gp = c1m0 + (size_t)e * 1792;
  if (t < 96){
    u16x8 v = *(const u16x8*)(gp + t * 8);
    #pragma unroll
    for (int i = 0; i < 8; ++i) g[t * 8 + i] = sigm(bf2f(v[i]));
  }
  __syncthreads();
  const u16* x0 = gp + 768;
  const u16* a0 = y10 + (size_t)e * 1536;
  const u16* a1 = y11 + (size_t)e * 1536;
  const u16* b0 = y20 + (size_t)e * 1280;
  const u16* b1 = y21 + (size_t)e * 1280;
  u16* o = msg2 + (size_t)e * 3712;
  const int grp = (t & 15) * 8;
  for (int r = t >> 4; r < 29; r += 16){
    u16x8 outv;
    if (r == 0){
      u16x8 v = *(const u16x8*)(x0 + grp);
      #pragma unroll
      for (int i = 0; i < 8; ++i){ float f = bf2f(v[i]); outv[i] = f2bf(f * sigm(f)); }
    } else if (r < 7){
      u16x8 v = *(const u16x8*)(x0 + r * 128 + grp);
      #pragma unroll
      for (int i = 0; i < 8; ++i)
        outv[i] = f2bf(bf2f(v[i]) * g[(r - 1) * 128 + grp + i]);
    } else if (r < 19){
      int k = (r < 13) ? r - 7 : r - 13;
      u16x8 va = *(const u16x8*)(a0 + ((r < 13) ? k * 128 : 768 + k * 128) + grp);
      u16x8 vb = *(const u16x8*)(a1 + ((r < 13) ? 768 + k * 128 : k * 128) + grp);
      #pragma unroll
      for (int i = 0; i < 8; ++i){
        float fa = bf2f(va[i]), fb = bf2f(vb[i]);
        float val = (r < 13) ? (fa - fb) : (fb + fa);
        outv[i] = f2bf(val * g[k * 128 + grp + i]);
      }
    } else {
      int k = (r < 24) ? r - 19 : r - 24;
      u16x8 va = *(const u16x8*)(b0 + ((r < 24) ? k * 128 : 640 + k * 128) + grp);
      u16x8 vb = *(const u16x8*)(b1 + ((r < 24) ? 640 + k * 128 : k * 128) + grp);
      #pragma unroll
      for (int i = 0; i < 8; ++i){
        float fa = bf2f(va[i]), fb = bf2f(vb[i]);
        float val = (r < 24) ? (fa - fb) : (fb + fa);
        outv[i] = f2bf(val * g[(1 + k) * 128 + grp + i]);
      }
    }
    *(u16x8*)(o + r * 128 + grp) = outv;
  }
}

// -------- recombine2 + envelope -> msg3T (c,m); m3x0 has ldc 1024 ----------
__global__ __launch_bounds__(128) void k_recomb2(
    const u16* __restrict__ m3x0, const u16* __restrict__ z10, const u16* __restrict__ z11,
    const u16* __restrict__ z20, const u16* __restrict__ z21, const float* __restrict__ env,
    u16* __restrict__ msg3T, const int* __restrict__ perm, int e0)
{
  __shared__ u16 s[6528];
  int e = blockIdx.x, c = threadIdx.x;
  {
    const u16* px0 = m3x0 + (size_t)e * 1024;
    const u16* pa0 = z10 + (size_t)e * 1536;
    const u16* pa1 = z11 + (size_t)e * 1536;
    const u16* pb0 = z20 + (size_t)e * 1280;
    const u16* pb1 = z21 + (size_t)e * 1280;
    for (int v = c; v < 112; v += 128) *(u16x8*)(&s[v * 8])        = *(const u16x8*)(px0 + v * 8);
    for (int v = c; v < 192; v += 128) *(u16x8*)(&s[896 + v * 8])  = *(const u16x8*)(pa0 + v * 8);
    for (int v = c; v < 192; v += 128) *(u16x8*)(&s[2432 + v * 8]) = *(const u16x8*)(pa1 + v * 8);
    for (int v = c; v < 160; v += 128) *(u16x8*)(&s[3968 + v * 8]) = *(const u16x8*)(pb0 + v * 8);
    for (int v = c; v < 160; v += 128) *(u16x8*)(&s[5248 + v * 8]) = *(const u16x8*)(pb1 + v * 8);
  }
  __syncthreads();
  float ev = env[perm[e0 + e]];
  const u16* x0 = s;
  const u16* a0 = s + 896;
  const u16* a1 = s + 2432;
  const u16* b0 = s + 3968;
  const u16* b1 = s + 5248;
  u16 v[32];
  #pragma unroll
  for (int r = 0; r < 7; ++r) v[r] = f2bf(bf2f(x0[r * 128 + c]) * ev);
  #pragma unroll
  for (int k = 0; k < 6; ++k){
    float orr = bf2f(a0[k * 128 + c]) - bf2f(a1[768 + k * 128 + c]);
    float oii = bf2f(a1[k * 128 + c]) + bf2f(a0[768 + k * 128 + c]);
    v[7 + k]  = f2bf(orr * ev);
    v[13 + k] = f2bf(oii * ev);
  }
  #pragma unroll
  for (int k = 0; k < 5; ++k){
    float orr = bf2f(b0[k * 128 + c]) - bf2f(b1[640 + k * 128 + c]);
    float oii = bf2f(b1[k * 128 + c]) + bf2f(b0[640 + k * 128 + c]);
    v[19 + k] = f2bf(orr * ev);
    v[24 + k] = f2bf(oii * ev);
  }
  v[29] = 0; v[30] = 0; v[31] = 0;
  u16* o = msg3T + (size_t)e * 4096 + c * 32;
  #pragma unroll
  for (int q = 0; q < 4; ++q)
    *(u16x8*)(o + q * 8) = *(const u16x8*)(&v[q * 8]);
}

// --------- Wigner inverse (MFMA, node-indexed run-gather, W dbuf) ----------
__global__ __launch_bounds__(256) void k_wig_inv(
    const u16* __restrict__ msg3T, const float* __restrict__ winv,
    const int* __restrict__ cnt, const int* __restrict__ soff,
    float* __restrict__ out, const int* __restrict__ perm, int e0, int cm)
{
  __shared__ u16 WV[2][2048];
  int d = blockIdx.x, tid = threadIdx.x;
  int cn = cnt[d];
  if (cn == 0) return;
  int runEnd = soff[d];           // post-scatter soff = run end
  int runStart = runEnd - cn;
  int start = runStart < e0 ? e0 : runStart;
  int end   = runEnd > e0 + cm ? e0 + cm : runEnd;
  if (start >= end) return;
  bool atom = (start != runStart) || (end != runEnd);

  int lane = tid & 63, w = tid >> 6;
  const int fr = lane & 15, fq = lane >> 4;
  const int jr = w * 16 + fr;

  auto stageW = [&](int buf, int pe){
    const float* wp = winv + (size_t)pe * 1421;
    for (int idx = tid; idx < 2048; idx += 256){
      int j = idx >> 5, m = idx & 31;
      float v = (j < 49 && m < 29) ? wp[j * 29 + m] : 0.f;
      WV[buf][j * 32 + (((m >> 3) ^ (j & 3)) << 3) + (m & 7)] = f2bf(v);
    }
  };

  f32x4 acc[8];
  #pragma unroll
  for (int ct = 0; ct < 8; ++ct) acc[ct] = (f32x4){0.f,0.f,0.f,0.f};

  stageW(0, perm[start]);
  __syncthreads();
  int b = 0;
  for (int t = start; t < end; ++t){
    if (t + 1 < end) stageW(b ^ 1, perm[t + 1]);
    bf16x8 a = __builtin_bit_cast(bf16x8,
        *(const u16x8*)&WV[b][jr * 32 + ((fq ^ (jr & 3)) << 3)]);
    const u16* bp = msg3T + (size_t)(t - e0) * 4096;
    #pragma unroll
    for (int ct = 0; ct < 8; ++ct){
      bf16x8 bo = __builtin_bit_cast(bf16x8,
          *(const u16x8*)(bp + (ct * 16 + fr) * 32 + fq * 8));
      acc[ct] = __builtin_amdgcn_mfma_f32_16x16x32_bf16(a, bo, acc[ct], 0, 0, 0);
    }
    __syncthreads();
    b ^= 1;
  }

  float* op = out + (size_t)d * 6272;
  if (atom){
    #pragma unroll
    for (int ct = 0; ct < 8; ++ct){
      int c = ct * 16 + fr;
      #pragma unroll
      for (int r = 0; r < 4; ++r){
        int j = w * 16 + fq * 4 + r;
        if (j < 49) atomicAdd(op + j * 128 + c, acc[ct][r]);
      }
    }
  } else {
    #pragma unroll
    for (int ct = 0; ct < 8; ++ct){
      int c = ct * 16 + fr;
      #pragma unroll
      for (int r = 0; r < 4; ++r){
        int j = w * 16 + fq * 4 + r;
        if (j < 49) op[j * 128 + c] = acc[ct][r];
      }
    }
  }
}

// ---------------------------------------------------------------------------
extern "C" void kernel_launch(void* const* d_in, const int* in_sizes, int n_in,
                              void* d_out, int out_size, void* d_ws, size_t ws_size,
                              hipStream_t stream)
{
  (void)in_sizes; (void)n_in;
  const float* x       = (const float*)d_in[0];
  const float* x_edge  = (const float*)d_in[1];
  const int*   eidx    = (const int*)d_in[3];
  const float* wig     = (const float*)d_in[4];
  const float* wig_inv = (const float*)d_in[5];
  const float* env     = (const float*)d_in[6];
  const float* rad_w0  = (const float*)d_in[7];
  const float* rad_b0  = (const float*)d_in[8];
  const float* ln0_s   = (const float*)d_in[9];
  const float* ln0_b   = (const float*)d_in[10];
  const float* rad_w1  = (const float*)d_in[11];
  const float* rad_b1  = (const float*)d_in[12];
  const float* ln1_s   = (const float*)d_in[13];
  const float* ln1_b   = (const float*)d_in[14];
  const float* rad_w2  = (const float*)d_in[15];
  const float* rad_b2  = (const float*)d_in[16];
  const float* c1w0    = (const float*)d_in[17];
  const float* c1b0    = (const float*)d_in[18];
  const float* c1w1    = (const float*)d_in[19];
  const float* c1w2    = (const float*)d_in[20];
  const float* c2w0    = (const float*)d_in[21];
  const float* c2b0    = (const float*)d_in[22];
  const float* c2w1    = (const float*)d_in[23];
  const float* c2w2    = (const float*)d_in[24];
  float* out = (float*)d_out;

  char* base = (char*)d_ws;
  size_t off = 0;
  auto alloc = [&](size_t bytes) -> char* {
    off = (off + 255) & ~(size_t)255;
    char* r = base + off;
    off += bytes;
    return r;
  };

  // ---- fixed area: bf16 weights + xT + sort arrays ----
  u16* wtR0  = (u16*)alloc((size_t)256  * 128  * 2);
  u16* wtR1  = (u16*)alloc((size_t)256  * 256  * 2);
  u16* wtR2  = (u16*)alloc((size_t)4608 * 256  * 2);
  u16* wtC10 = (u16*)alloc((size_t)1792 * 1792 * 2);   // padded: 1664 -> 1792 rows
  u16* wtC11 = (u16*)alloc((size_t)1536 * 1536 * 2);
  u16* wtC12 = (u16*)alloc((size_t)1280 * 1280 * 2);
  u16* wtC20 = (u16*)alloc((size_t)1024 * 896  * 2);   // padded: 896 -> 1024 rows
  u16* wtC21 = (u16*)alloc((size_t)1536 * 768  * 2);
  u16* wtC22 = (u16*)alloc((size_t)1280 * 640  * 2);
  u16* xT    = (u16*)alloc((size_t)NN * 8192 * 2);
  int* cnt   = (int*)alloc(NN * 4);
  int* soff  = (int*)alloc(NN * 4);
  int* perm  = (int*)alloc(E_NUM * 4);

  // ---- chunk size (per-edge: 256+512+512+9216+14848+14848 = 40,192 B) ----
  size_t fixed_end = (off + 65536) & ~(size_t)65535;
  size_t avail = (ws_size > fixed_end + (1u << 20)) ? (ws_size - fixed_end - (1u << 20)) : 0;
  long CH0 = (long)(avail / 40960);
  if (CH0 > E_NUM) CH0 = E_NUM;
  if (CH0 < 64) CH0 = 64;
  int nch = (int)((E_NUM + CH0 - 1) / CH0);
  int CH = (E_NUM + nch - 1) / nch;          // equalized chunks
  if (CH > CH0) CH = (int)CH0;

  off = fixed_end;
  const size_t C = (size_t)CH;
  u16*   xe   = (u16*)alloc(C * 128 * 2);
  u16*   h0   = (u16*)alloc(C * 256 * 2);
  u16*   h1   = (u16*)alloc(C * 256 * 2);
  u16* region1 = (u16*)alloc(C * 4608 * 2);   // xrad -> msg2
  u16* region2 = (u16*)alloc(C * 7424 * 2);   // msgS -> conv2 outs
  u16* region3 = (u16*)alloc(C * 7424 * 2);   // conv1 outs -> msg3T
  u16* xrad = region1;
  u16* msg2 = region1;
  u16* msgS = region2;
  u16* m3x0 = region2;                 // (C,1024) padded
  u16* z10  = region2 + C * 1024;      // (C,1536)
  u16* z11  = region2 + C * 2560;      // (C,1536)
  u16* z20  = region2 + C * 4096;      // (C,1280)
  u16* z21  = region2 + C * 5376;      // (C,1280)
  u16* c1m0b = region3;                // (C,1792) padded
  u16* y10   = region3 + C * 1792;     // (C,1536)
  u16* y11   = region3 + C * 3328;     // (C,1536)
  u16* y20   = region3 + C * 4864;     // (C,1280)
  u16* y21   = region3 + C * 6144;     // (C,1280)
  u16* msg3T = region3;                // (C,4096) transposed (c,m)

  hipMemsetAsync(d_out, 0, (size_t)out_size * sizeof(float), stream);
  hipMemsetAsync(cnt, 0, NN * 4, stream);
  // zero padded weight buffers (pad rows must be 0)
  k_zero16<<<2048, 256, 0, stream>>>(wtC10, 1792 * 1792);
  k_zero16<<<2048, 256, 0, stream>>>(wtC20, 1024 * 896);

  // dst counting sort -> perm ; x transpose
  k_hist<<<(E_NUM + 255) / 256, 256, 0, stream>>>(eidx, cnt);
  k_scan<<<1, 256, 0, stream>>>(cnt, soff);
  k_scatter<<<(E_NUM + 255) / 256, 256, 0, stream>>>(eidx, soff, perm);
  k_xpose<<<NN, 256, 0, stream>>>(x, xT);

  auto tw = [&](const float* in, u16* o, int K, int N){
    k_transpose_w<<<dim3(N / 32, K / 32), 256, 0, stream>>>(in, o, K, N);
  };
  tw(rad_w0, wtR0, 128, 256);
  tw(rad_w1, wtR1, 256, 256);
  tw(rad_w2, wtR2, 256, 4608);
  tw(c1w0, wtC10, 1792, 1664);   // rows 1664..1791 stay zero
  tw(c1w1, wtC11, 1536, 1536);
  tw(c1w2, wtC12, 1280, 1280);
  tw(c2w0, wtC20, 896, 896);     // rows 896..1023 stay zero
  tw(c2w1, wtC21, 768, 1536);
  tw(c2w2, wtC22, 640, 1280);

  for (int e0 = 0; e0 < E_NUM; e0 += CH){
    int cm = E_NUM - e0 < CH ? E_NUM - e0 : CH;
    int mb = (cm + 127) / 128;

    k_gather_xe<<<cm, 128, 0, stream>>>(x_edge, perm, xe, e0);

    // radial MLP: 2 fused gemm+LN+SiLU + wide gemm (N=4608 = 18*256)
    k_gemm_ln<<<mb, 512, 0, stream>>>(xe, 128, wtR0, rad_b0, ln0_s, ln0_b, h0, cm, 128);
    k_gemm_ln<<<mb, 512, 0, stream>>>(h0, 256, wtR1, rad_b1, ln1_s, ln1_b, h1, cm, 256);
    k_gemm_bt256<<<dim3(4608 / 256, mb), 512, 0, stream>>>(
        h1, 256, wtR2, rad_b2, 4608, nullptr, xrad, 4608, cm, 256);

    // wigner forward (MFMA, B-frags from global xT)
    k_wig_fwd<<<cm, 256, 0, stream>>>(xT, eidx, wig, xrad, msgS, perm, e0);

    // conv1: one segmented launch (all N % 256 == 0)
    {
      Seg5 g;
      int b = 0;
      auto mk = [&](const u16* A, const u16* B, u16* Cb, const float* bias,
                    int N, int K, int Nb) -> Seg {
        Seg s{A, B, Cb, bias, cm, N, K, 7424, b, Nb};
        b += (N >> 8) * mb;
        return s;
      };
      g.s[0] = mk(msgS,        wtC10, c1m0b, c1b0,   1792, 1792, 1664);
      g.s[1] = mk(msgS + 1792, wtC11, y10,   nullptr, 1536, 1536, 0);
      g.s[2] = mk(msgS + 3328, wtC11, y11,   nullptr, 1536, 1536, 0);
      g.s[3] = mk(msgS + 4864, wtC12, y20,   nullptr, 1280, 1280, 0);
      g.s[4] = mk(msgS + 6144, wtC12, y21,   nullptr, 1280, 1280, 0);
      g.nwg = b;
      k_gemm_seg<<<b, 512, 0, stream>>>(g);
    }

    k_gate<<<cm, 256, 0, stream>>>(c1m0b, y10, y11, y20, y21, msg2);

    // conv2: one segmented launch
    {
      Seg5 g;
      int b = 0;
      auto mk = [&](const u16* A, const u16* B, u16* Cb, const float* bias,
                    int N, int K, int Nb) -> Seg {
        Seg s{A, B, Cb, bias, cm, N, K, 3712, b, Nb};
        b += (N >> 8) * mb;
        return s;
      };
      g.s[0] = mk(msg2,        wtC20, m3x0, c2b0,   1024, 896, 896);
      g.s[1] = mk(msg2 + 896,  wtC21, z10,  nullptr, 1536, 768, 0);
      g.s[2] = mk(msg2 + 1664, wtC21, z11,  nullptr, 1536, 768, 0);
      g.s[3] = mk(msg2 + 2432, wtC22, z20,  nullptr, 1280, 640, 0);
      g.s[4] = mk(msg2 + 3072, wtC22, z21,  nullptr, 1280, 640, 0);
      g.nwg = b;
      k_gemm_seg<<<b, 512, 0, stream>>>(g);
    }

    k_recomb2<<<cm, 128, 0, stream>>>(m3x0, z10, z11, z20, z21, env, msg3T, perm, e0);

    // wigner inverse: node-indexed run-gather, W dbuf
    k_wig_inv<<<NN, 256, 0, stream>>>(msg3T, wig_inv, cnt, soff, out, perm, e0, cm);
  }
}

// Round 16
// 2183.121 us; speedup vs baseline: 1.1382x; 1.0554x over previous
//
#include <hip/hip_runtime.h>
#include <stdint.h>

// ---------------------------------------------------------------------------
// Edgewise (eSCN SO(2) conv block), MI355X gfx950.
// Round 16: (1) k_gemm_seg uses default blockIdx (contiguous-XCD swizzle
// caused segment-level XCD load imbalance; T1 inapplicable at 14% HBM /
// L3-fit); (2) 9 weight transposes folded into one segmented launch; pad
// zeroing restricted to actual pad rows. Rest identical to round 15.
// ---------------------------------------------------------------------------

#define E_NUM   20000
#define NN      5000

typedef uint16_t u16;
typedef __bf16  bf16x8 __attribute__((ext_vector_type(8)));
typedef float   f32x4  __attribute__((ext_vector_type(4)));
typedef uint16_t u16x8 __attribute__((ext_vector_type(8)));

__device__ __forceinline__ float bf2f(u16 h){
  uint32_t u = ((uint32_t)h) << 16;
  return __builtin_bit_cast(float, u);
}
__device__ __forceinline__ u16 f2bf(float f){
  uint32_t u = __builtin_bit_cast(uint32_t, f);
  u += 0x7fffu + ((u >> 16) & 1u);
  return (u16)(u >> 16);
}
__device__ __forceinline__ float sigm(float x){ return 1.f / (1.f + __expf(-x)); }

__device__ __forceinline__ void gload16(const void* g, void* l){
  __builtin_amdgcn_global_load_lds(
      (const __attribute__((address_space(1))) void*)g,
      (__attribute__((address_space(3))) void*)l, 16, 0, 0);
}

// ----------------------- dst counting sort ---------------------------------
__global__ void k_hist(const int* __restrict__ eidx, int* __restrict__ cnt){
  int e = blockIdx.x * 256 + threadIdx.x;
  if (e < E_NUM) atomicAdd(&cnt[eidx[E_NUM + e]], 1);
}
__global__ __launch_bounds__(256) void k_scan(const int* __restrict__ cnt,
                                              int* __restrict__ off){
  __shared__ int part[256];
  int t = threadIdx.x;
  int s = 0;
  #pragma unroll
  for (int i = 0; i < 20; ++i){
    int idx = t * 20 + i;
    if (idx < NN) s += cnt[idx];
  }
  part[t] = s;
  __syncthreads();
  if (t == 0){
    int run = 0;
    for (int i = 0; i < 256; ++i){ int v = part[i]; part[i] = run; run += v; }
  }
  __syncthreads();
  int run = part[t];
  #pragma unroll
  for (int i = 0; i < 20; ++i){
    int idx = t * 20 + i;
    if (idx < NN){ off[idx] = run; run += cnt[idx]; }
  }
}
__global__ void k_scatter(const int* __restrict__ eidx, int* __restrict__ off,
                          int* __restrict__ perm){
  int e = blockIdx.x * 256 + threadIdx.x;
  if (e < E_NUM){
    int pos = atomicAdd(&off[eidx[E_NUM + e]], 1);
    perm[pos] = e;
  }
}

// ---------------- segmented weight transpose (all 9 in one launch) ---------
struct TW { const float* in; u16* out; int K, N, blk0; };
struct TW9 { TW t[9]; };

__global__ __launch_bounds__(256) void k_transpose_all(TW9 g){
  __shared__ float t[32][33];
  int bid = blockIdx.x;
  TW s = g.t[8];
  #pragma unroll
  for (int i = 7; i >= 0; --i) if (bid < g.t[i + 1].blk0) s = g.t[i];
  int local = bid - s.blk0;
  int nx = s.N >> 5;
  int nb = (local % nx) * 32, kb = (local / nx) * 32;
  int tx = threadIdx.x & 31, ty = threadIdx.x >> 5;   // 32x8
  for (int i = ty; i < 32; i += 8)
    t[i][tx] = s.in[(size_t)(kb + i) * s.N + (nb + tx)];
  __syncthreads();
  for (int i = ty; i < 32; i += 8)
    s.out[(size_t)(nb + i) * s.K + (kb + tx)] = f2bf(t[tx][i]);
}

// zero-fill helper (pads weight buffers)
__global__ void k_zero16(u16* __restrict__ p, int n){
  int i = blockIdx.x * 256 + threadIdx.x;
  int stride = gridDim.x * 256;
  for (; i < n; i += stride) p[i] = 0;
}

// ------------- x -> xT bf16, [node][c=128][k=64 padded], once --------------
__global__ __launch_bounds__(256) void k_xpose(const float* __restrict__ x,
                                               u16* __restrict__ xT){
  __shared__ float t[6272];
  int n = blockIdx.x, tid = threadIdx.x;
  const float* xp = x + (size_t)n * 6272;
  for (int i = tid; i < 6272; i += 256) t[i] = xp[i];
  __syncthreads();
  int c = tid >> 1;
  int kh = (tid & 1) * 32;
  u16* o = xT + (size_t)n * 8192 + c * 64 + kh;
  #pragma unroll
  for (int q = 0; q < 4; ++q){
    u16x8 h;
    #pragma unroll
    for (int i = 0; i < 8; ++i){
      int k = kh + q * 8 + i;
      h[i] = (k < 49) ? f2bf(t[k * 128 + c]) : (u16)0;
    }
    *(u16x8*)(o + q * 8) = h;
  }
}

// gather x_edge rows in permuted order -> bf16
__global__ void k_gather_xe(const float* __restrict__ x_edge,
                            const int* __restrict__ perm,
                            u16* __restrict__ xe, int e0){
  int el = blockIdx.x, c = threadIdx.x;
  int pe = perm[e0 + el];
  xe[(size_t)el * 128 + c] = f2bf(x_edge[(size_t)pe * 128 + c]);
}

// ---------------- GEMM core: 128x256 tile, 8 waves, 512 thr ----------------
struct Seg {
  const u16* A; const u16* B; u16* C; const float* bias;
  int M, N, K, lda, blk0, Nb;
};
struct Seg5 { Seg s[5]; int nwg; };

__device__ __forceinline__ void gemm_tile256(
    const u16* __restrict__ A, int lda, const u16* __restrict__ B,
    const float* __restrict__ bias, int Nb, u16* __restrict__ Cb,
    float* __restrict__ Cf, int ldc, int M, int K,
    int bm, int bn, u16* As /*2*4096*/, u16* Bs /*2*8192*/)
{
  const int tid = threadIdx.x, lane = tid & 63, w = tid >> 6;
  const int fr = lane & 15, fq = lane >> 4;
  const int row0 = bm * 128, col0 = bn * 256;

  const int lr = lane >> 2, lg = lane & 3;
  int rA = w * 16 + lr;
  int gA = lg ^ ((rA >> 1) & 3);
  int grA = row0 + rA; if (grA > M - 1) grA = M - 1;
  const u16* aS = A + (size_t)grA * lda + gA * 8;
  int rB0 = w * 32 + lr, rB1 = rB0 + 16;
  int gB0 = lg ^ ((rB0 >> 1) & 3), gB1 = lg ^ ((rB1 >> 1) & 3);
  const u16* bS0 = B + (size_t)(col0 + rB0) * K + gB0 * 8;
  const u16* bS1 = B + (size_t)(col0 + rB1) * K + gB1 * 8;
  const int dA  = (w * 16) * 32;
  const int dB0 = (w * 32) * 32;
  const int dB1 = (w * 32 + 16) * 32;

  int aoff[4], boff[4];
  #pragma unroll
  for (int mi = 0; mi < 4; ++mi){
    int r = (w & 1) * 64 + mi * 16 + fr;
    aoff[mi] = r * 32 + (fq ^ ((r >> 1) & 3)) * 8;
  }
  #pragma unroll
  for (int ni = 0; ni < 4; ++ni){
    int cc = (w >> 1) * 64 + ni * 16 + fr;
    boff[ni] = cc * 32 + (fq ^ ((cc >> 1) & 3)) * 8;
  }

  f32x4 acc[4][4];
  #pragma unroll
  for (int i = 0; i < 4; ++i)
    #pragma unroll
    for (int j = 0; j < 4; ++j) acc[i][j] = (f32x4){0.f, 0.f, 0.f, 0.f};

  auto stage = [&](int buf, int k0){
    gload16(aS + k0, &As[buf * 4096 + dA]);
    gload16(bS0 + k0, &Bs[buf * 8192 + dB0]);
    gload16(bS1 + k0, &Bs[buf * 8192 + dB1]);
  };

  stage(0, 0);
  __syncthreads();
  int cur = 0;
  for (int k0 = 0; k0 < K; k0 += 32){
    if (k0 + 32 < K) stage(cur ^ 1, k0 + 32);
    bf16x8 af[4], bfv[4];
    #pragma unroll
    for (int mi = 0; mi < 4; ++mi)
      af[mi] = __builtin_bit_cast(bf16x8, *(const u16x8*)&As[cur * 4096 + aoff[mi]]);
    #pragma unroll
    for (int ni = 0; ni < 4; ++ni)
      bfv[ni] = __builtin_bit_cast(bf16x8, *(const u16x8*)&Bs[cur * 8192 + boff[ni]]);
    #pragma unroll
    for (int mi = 0; mi < 4; ++mi)
      #pragma unroll
      for (int ni = 0; ni < 4; ++ni)
        acc[mi][ni] = __builtin_amdgcn_mfma_f32_16x16x32_bf16(af[mi], bfv[ni], acc[mi][ni], 0, 0, 0);
    __syncthreads();
    cur ^= 1;
  }

  #pragma unroll
  for (int ni = 0; ni < 4; ++ni){
    int col = col0 + (w >> 1) * 64 + ni * 16 + fr;
    float bv = (bias && col < Nb) ? bias[col] : 0.f;
    #pragma unroll
    for (int mi = 0; mi < 4; ++mi){
      #pragma unroll
      for (int i = 0; i < 4; ++i){
        int row = row0 + (w & 1) * 64 + mi * 16 + fq * 4 + i;
        if (row < M){
          float v = acc[mi][ni][i] + bv;
          if (Cb) Cb[(size_t)row * ldc + col] = f2bf(v);
          else    Cf[(size_t)row * ldc + col] = v;
        }
      }
    }
  }
}

// plain wide GEMM (radial w2); N % 256 == 0, ldc == N
__global__ __launch_bounds__(512) void k_gemm_bt256(
    const u16* __restrict__ A, int lda, const u16* __restrict__ B,
    const float* __restrict__ bias, int Nb, float* __restrict__ Cf,
    u16* __restrict__ Cb, int ldc, int M, int K)
{
  __shared__ u16 As[2 * 4096];
  __shared__ u16 Bs[2 * 8192];
  gemm_tile256(A, lda, B, bias, Nb, Cb, Cf, ldc, M, K,
               blockIdx.y, blockIdx.x, As, Bs);
}

// segmented GEMM: 5 independent GEMMs (N % 256 == 0) in one launch.
// Default blockIdx mapping (round-robin over XCDs) balances segments with
// different K across XCDs.
__global__ __launch_bounds__(512) void k_gemm_seg(Seg5 g)
{
  __shared__ u16 As[2 * 4096];
  __shared__ u16 Bs[2 * 8192];
  int wgid = blockIdx.x;
  Seg sg = g.s[4];
  if (wgid < g.s[4].blk0) sg = g.s[3];
  if (wgid < g.s[3].blk0) sg = g.s[2];
  if (wgid < g.s[2].blk0) sg = g.s[1];
  if (wgid < g.s[1].blk0) sg = g.s[0];
  int local = wgid - sg.blk0;
  int nbx = sg.N >> 8;
  int bn = local % nbx;
  int bm = local / nbx;
  gemm_tile256(sg.A, sg.lda, sg.B, sg.bias, sg.Nb, sg.C, nullptr, sg.N,
               sg.M, sg.K, bm, bn, As, Bs);
}

// ------------------ fused GEMM(N=256) + LayerNorm + SiLU -------------------
__global__ __launch_bounds__(512) void k_gemm_ln(
    const u16* __restrict__ A, int lda, const u16* __restrict__ B /*(256,K)*/,
    const float* __restrict__ bias, const float* __restrict__ lns,
    const float* __restrict__ lnb, u16* __restrict__ out, int M, int K)
{
  __shared__ u16 As[2][4096];    // 128 x 32
  __shared__ u16 Bs[2][8192];    // 256 x 32
  __shared__ float rsum[128][4], rsq[128][4];
  const int tid = threadIdx.x, lane = tid & 63, w = tid >> 6;
  const int fr = lane & 15, fq = lane >> 4;
  const int bm = blockIdx.x, row0 = bm * 128;

  const int lr = lane >> 2, lg = lane & 3;
  int rA = w * 16 + lr;
  int gA = lg ^ ((rA >> 1) & 3);
  int grA = row0 + rA; if (grA > M - 1) grA = M - 1;
  const u16* aS = A + (size_t)grA * lda + gA * 8;
  int rB0 = w * 32 + lr, rB1 = rB0 + 16;
  int gB0 = lg ^ ((rB0 >> 1) & 3), gB1 = lg ^ ((rB1 >> 1) & 3);
  const u16* bS0 = B + (size_t)rB0 * K + gB0 * 8;
  const u16* bS1 = B + (size_t)rB1 * K + gB1 * 8;
  const int dA  = (w * 16) * 32;
  const int dB0 = (w * 32) * 32;
  const int dB1 = (w * 32 + 16) * 32;

  int aoff[4], boff[4];
  #pragma unroll
  for (int mi = 0; mi < 4; ++mi){
    int r = (w & 1) * 64 + mi * 16 + fr;
    aoff[mi] = r * 32 + (fq ^ ((r >> 1) & 3)) * 8;
  }
  #pragma unroll
  for (int ni = 0; ni < 4; ++ni){
    int ccol = (w >> 1) * 64 + ni * 16 + fr;
    boff[ni] = ccol * 32 + (fq ^ ((ccol >> 1) & 3)) * 8;
  }

  f32x4 acc[4][4];
  #pragma unroll
  for (int i = 0; i < 4; ++i)
    #pragma unroll
    for (int j = 0; j < 4; ++j) acc[i][j] = (f32x4){0.f, 0.f, 0.f, 0.f};

  auto stage = [&](int buf, int k0){
    gload16(aS + k0, &As[buf][dA]);
    gload16(bS0 + k0, &Bs[buf][dB0]);
    gload16(bS1 + k0, &Bs[buf][dB1]);
  };

  stage(0, 0);
  __syncthreads();
  int cur = 0;
  for (int k0 = 0; k0 < K; k0 += 32){
    if (k0 + 32 < K) stage(cur ^ 1, k0 + 32);
    bf16x8 af[4], bfv[4];
    #pragma unroll
    for (int mi = 0; mi < 4; ++mi)
      af[mi] = __builtin_bit_cast(bf16x8, *(const u16x8*)&As[cur][aoff[mi]]);
    #pragma unroll
    for (int ni = 0; ni < 4; ++ni)
      bfv[ni] = __builtin_bit_cast(bf16x8, *(const u16x8*)&Bs[cur][boff[ni]]);
    #pragma unroll
    for (int mi = 0; mi < 4; ++mi)
      #pragma unroll
      for (int ni = 0; ni < 4; ++ni)
        acc[mi][ni] = __builtin_amdgcn_mfma_f32_16x16x32_bf16(af[mi], bfv[ni], acc[mi][ni], 0, 0, 0);
    __syncthreads();
    cur ^= 1;
  }

  const int cq = w >> 1;
  float bv[4], sc[4], bb[4];
  #pragma unroll
  for (int ni = 0; ni < 4; ++ni){
    int col = cq * 64 + ni * 16 + fr;
    bv[ni] = bias[col]; sc[ni] = lns[col]; bb[ni] = lnb[col];
  }
  #pragma unroll
  for (int mi = 0; mi < 4; ++mi){
    #pragma unroll
    for (int i = 0; i < 4; ++i){
      float s1 = 0.f, s2 = 0.f;
      #pragma unroll
      for (int ni = 0; ni < 4; ++ni){
        float v = acc[mi][ni][i] + bv[ni];
        s1 += v; s2 += v * v;
      }
      #pragma unroll
      for (int off = 1; off < 16; off <<= 1){
        s1 += __shfl_xor(s1, off);
        s2 += __shfl_xor(s2, off);
      }
      if (fr == 0){
        int r = (w & 1) * 64 + mi * 16 + fq * 4 + i;
        rsum[r][cq] = s1; rsq[r][cq] = s2;
      }
    }
  }
  __syncthreads();
  #pragma unroll
  for (int mi = 0; mi < 4; ++mi){
    #pragma unroll
    for (int i = 0; i < 4; ++i){
      int r = (w & 1) * 64 + mi * 16 + fq * 4 + i;
      float S1 = rsum[r][0] + rsum[r][1] + rsum[r][2] + rsum[r][3];
      float S2 = rsq[r][0] + rsq[r][1] + rsq[r][2] + rsq[r][3];
      float mu  = S1 * (1.f / 256.f);
      float var = S2 * (1.f / 256.f) - mu * mu;
      float rs  = rsqrtf(var + 1e-5f);
      int row = row0 + r;
      if (row < M){
        #pragma unroll
        for (int ni = 0; ni < 4; ++ni){
          int col = cq * 64 + ni * 16 + fr;
          float nv = (acc[mi][ni][i] + bv[ni] - mu) * rs * sc[ni] + bb[ni];
          out[(size_t)row * 256 + col] = f2bf(nv * sigm(nv));
        }
      }
    }
  }
}

// --------------------- Wigner forward (MFMA, permuted) ---------------------
__global__ __launch_bounds__(256) void k_wig_fwd(
    const u16* __restrict__ xT, const int* __restrict__ eidx,
    const float* __restrict__ wig, const u16* __restrict__ xrad,
    u16* __restrict__ msgS, const int* __restrict__ perm, int e0)
{
  __shared__ u16 WL[32 * 64];
  int el = blockIdx.x, tid = threadIdx.x;
  int eg = perm[e0 + el];
  int lane = tid & 63, w = tid >> 6;

  const float* wp = wig + (size_t)eg * 1421;
  for (int idx = tid; idx < 2048; idx += 256){
    int m = idx >> 6, k = idx & 63;
    float v = (m < 29 && k < 49) ? wp[m * 49 + k] : 0.f;
    WL[m * 64 + ((((k >> 3) ^ (m & 7))) << 3) + (k & 7)] = f2bf(v);
  }

  const int fr = lane & 15, fq = lane >> 4;
  const int colbase = w * 64;
  int node = eidx[((w >> 1) ? E_NUM : 0) + eg];
  const u16* xb = xT + (size_t)node * 8192;
  bf16x8 bfv[4][2];
  #pragma unroll
  for (int ct = 0; ct < 4; ++ct)
    #pragma unroll
    for (int ks = 0; ks < 2; ++ks){
      int cc = ((w & 1) * 64) + ct * 16 + fr;       // within-node column
      bfv[ct][ks] = __builtin_bit_cast(bf16x8,
          *(const u16x8*)(xb + cc * 64 + (ks * 4 + fq) * 8));
    }
  __syncthreads();

  bf16x8 af[2][2];
  #pragma unroll
  for (int mt = 0; mt < 2; ++mt)
    #pragma unroll
    for (int ks = 0; ks < 2; ++ks){
      int m = mt * 16 + fr;
      int g = ks * 4 + fq;
      af[mt][ks] = __builtin_bit_cast(bf16x8,
          *(const u16x8*)&WL[m * 64 + ((g ^ (m & 7)) << 3)]);
    }
  f32x4 acc[2][4];
  #pragma unroll
  for (int mt = 0; mt < 2; ++mt)
    #pragma unroll
    for (int ct = 0; ct < 4; ++ct) acc[mt][ct] = (f32x4){0.f,0.f,0.f,0.f};
  #pragma unroll
  for (int mt = 0; mt < 2; ++mt)
    #pragma unroll
    for (int ct = 0; ct < 4; ++ct)
      #pragma unroll
      for (int ks = 0; ks < 2; ++ks)
        acc[mt][ct] = __builtin_amdgcn_mfma_f32_16x16x32_bf16(
            af[mt][ks], bfv[ct][ks], acc[mt][ct], 0, 0, 0);

  const u16* xr = xrad + (size_t)el * 4608;
  u16* o = msgS + (size_t)el * 7424;
  #pragma unroll
  for (int mt = 0; mt < 2; ++mt)
    #pragma unroll
    for (int ct = 0; ct < 4; ++ct){
      int col = colbase + ct * 16 + fr;
      #pragma unroll
      for (int r = 0; r < 4; ++r){
        int m = mt * 16 + fq * 4 + r;
        if (m < 29){
          int rr = (m < 13) ? m : (m < 24 ? m - 6 : m - 11);
          o[m * 256 + col] = f2bf(acc[mt][ct][r] * bf2f(xr[rr * 256 + col]));
        }
      }
    }
}

// -------------------- gate + recombine (conv1, u16x8) ----------------------
// c1m0 rows have ldc 1792 (last 128 cols = pad).
__global__ __launch_bounds__(256) void k_gate(
    const u16* __restrict__ c1m0, const u16* __restrict__ y10, const u16* __restrict__ y11,
    const u16* __restrict__ y20, const u16* __restrict__ y21, u16* __restrict__ msg2)
{
  int e = blockIdx.x, t = threadIdx.x;
  __shared__ float g[768];
  const u16* gp = c1m0 + (size_t)e * 1792;
  if (t < 96){
    u16x8 v = *(const u16x8*)(gp + t * 8);
    #pragma unroll
    for (int i = 0; i < 8; ++i) g[t * 8 + i] = sigm(bf2f(v[i]));
  }
  __syncthreads();
  const u16* x0 = gp + 768;
  const u16* a0 = y10 + (size_t)e * 1536;
  const u16* a1 = y11 + (size_t)e * 1536;
  const u16* b0 = y20 + (size_t)e * 1280;
  const u16* b1 = y21 + (size_t)e * 1280;
  u16* o = msg2 + (size_t)e * 3712;
  const int grp = (t & 15) * 8;
  for (int r = t >> 4; r < 29; r += 16){
    u16x8 outv;
    if (r == 0){
      u16x8 v = *(const u16x8*)(x0 + grp);
      #pragma unroll
      for (int i = 0; i < 8; ++i){ float f = bf2f(v[i]); outv[i] = f2bf(f * sigm(f)); }
    } else if (r < 7){
      u16x8 v = *(const u16x8*)(x0 + r * 128 + grp);
      #pragma unroll
      for (int i = 0; i < 8; ++i)
        outv[i] = f2bf(bf2f(v[i]) * g[(r - 1) * 128 + grp + i]);
    } else if (r < 19){
      int k = (r < 13) ? r - 7 : r - 13;
      u16x8 va = *(const u16x8*)(a0 + ((r < 13) ? k * 128 : 768 + k * 128) + grp);
      u16x8 vb = *(const u16x8*)(a1 + ((r < 13) ? 768 + k * 128 : k * 128) + grp);
      #pragma unroll
      for (int i = 0; i < 8; ++i){
        float fa = bf2f(va[i]), fb = bf2f(vb[i]);
        float val = (r < 13) ? (fa - fb) : (fb + fa);
        outv[i] = f2bf(val * g[k * 128 + grp + i]);
      }
    } else {
      int k = (r < 24) ? r - 19 : r - 24;
      u16x8 va = *(const u16x8*)(b0 + ((r < 24) ? k * 128 : 640 + k * 128) + grp);
      u16x8 vb = *(const u16x8*)(b1 + ((r < 24) ? 640 + k * 128 : k * 128) + grp);
      #pragma unroll
      for (int i = 0; i < 8; ++i){
        float fa = bf2f(va[i]), fb = bf2f(vb[i]);
        float val = (r < 24) ? (fa - fb) : (fb + fa);
        outv[i] = f2bf(val * g[(1 + k) * 128 + grp + i]);
      }
    }
    *(u16x8*)(o + r * 128 + grp) = outv;
  }
}

// -------- recombine2 + envelope -> msg3T (c,m); m3x0 has ldc 1024 ----------
__global__ __launch_bounds__(128) void k_recomb2(
    const u16* __restrict__ m3x0, const u16* __restrict__ z10, const u16* __restrict__ z11,
    const u16* __restrict__ z20, const u16* __restrict__ z21, const float* __restrict__ env,
    u16* __restrict__ msg3T, const int* __restrict__ perm, int e0)
{
  __shared__ u16 s[6528];
  int e = blockIdx.x, c = threadIdx.x;
  {
    const u16* px0 = m3x0 + (size_t)e * 1024;
    const u16* pa0 = z10 + (size_t)e * 1536;
    const u16* pa1 = z11 + (size_t)e * 1536;
    const u16* pb0 = z20 + (size_t)e * 1280;
    const u16* pb1 = z21 + (size_t)e * 1280;
    for (int v = c; v < 112; v += 128) *(u16x8*)(&s[v * 8])        = *(const u16x8*)(px0 + v * 8);
    for (int v = c; v < 192; v += 128) *(u16x8*)(&s[896 + v * 8])  = *(const u16x8*)(pa0 + v * 8);
    for (int v = c; v < 192; v += 128) *(u16x8*)(&s[2432 + v * 8]) = *(const u16x8*)(pa1 + v * 8);
    for (int v = c; v < 160; v += 128) *(u16x8*)(&s[3968 + v * 8]) = *(const u16x8*)(pb0 + v * 8);
    for (int v = c; v < 160; v += 128) *(u16x8*)(&s[5248 + v * 8]) = *(const u16x8*)(pb1 + v * 8);
  }
  __syncthreads();
  float ev = env[perm[e0 + e]];
  const u16* x0 = s;
  const u16* a0 = s + 896;
  const u16* a1 = s + 2432;
  const u16* b0 = s + 3968;
  const u16* b1 = s + 5248;
  u16 v[32];
  #pragma unroll
  for (int r = 0; r < 7; ++r) v[r] = f2bf(bf2f(x0[r * 128 + c]) * ev);
  #pragma unroll
  for (int k = 0; k < 6; ++k){
    float orr = bf2f(a0[k * 128 + c]) - bf2f(a1[768 + k * 128 + c]);
    float oii = bf2f(a1[k * 128 + c]) + bf2f(a0[768 + k * 128 + c]);
    v[7 + k]  = f2bf(orr * ev);
    v[13 + k] = f2bf(oii * ev);
  }
  #pragma unroll
  for (int k = 0; k < 5; ++k){
    float orr = bf2f(b0[k * 128 + c]) - bf2f(b1[640 + k * 128 + c]);
    float oii = bf2f(b1[k * 128 + c]) + bf2f(b0[640 + k * 128 + c]);
    v[19 + k] = f2bf(orr * ev);
    v[24 + k] = f2bf(oii * ev);
  }
  v[29] = 0; v[30] = 0; v[31] = 0;
  u16* o = msg3T + (size_t)e * 4096 + c * 32;
  #pragma unroll
  for (int q = 0; q < 4; ++q)
    *(u16x8*)(o + q * 8) = *(const u16x8*)(&v[q * 8]);
}

// --------- Wigner inverse (MFMA, node-indexed run-gather, W dbuf) ----------
__global__ __launch_bounds__(256) void k_wig_inv(
    const u16* __restrict__ msg3T, const float* __restrict__ winv,
    const int* __restrict__ cnt, const int* __restrict__ soff,
    float* __restrict__ out, const int* __restrict__ perm, int e0, int cm)
{
  __shared__ u16 WV[2][2048];
  int d = blockIdx.x, tid = threadIdx.x;
  int cn = cnt[d];
  if (cn == 0) return;
  int runEnd = soff[d];           // post-scatter soff = run end
  int runStart = runEnd - cn;
  int start = runStart < e0 ? e0 : runStart;
  int end   = runEnd > e0 + cm ? e0 + cm : runEnd;
  if (start >= end) return;
  bool atom = (start != runStart) || (end != runEnd);

  int lane = tid & 63, w = tid >> 6;
  const int fr = lane & 15, fq = lane >> 4;
  const int jr = w * 16 + fr;

  auto stageW = [&](int buf, int pe){
    const float* wp = winv + (size_t)pe * 1421;
    for (int idx = tid; idx < 2048; idx += 256){
      int j = idx >> 5, m = idx & 31;
      float v = (j < 49 && m < 29) ? wp[j * 29 + m] : 0.f;
      WV[buf][j * 32 + (((m >> 3) ^ (j & 3)) << 3) + (m & 7)] = f2bf(v);
    }
  };

  f32x4 acc[8];
  #pragma unroll
  for (int ct = 0; ct < 8; ++ct) acc[ct] = (f32x4){0.f,0.f,0.f,0.f};

  stageW(0, perm[start]);
  __syncthreads();
  int b = 0;
  for (int t = start; t < end; ++t){
    if (t + 1 < end) stageW(b ^ 1, perm[t + 1]);
    bf16x8 a = __builtin_bit_cast(bf16x8,
        *(const u16x8*)&WV[b][jr * 32 + ((fq ^ (jr & 3)) << 3)]);
    const u16* bp = msg3T + (size_t)(t - e0) * 4096;
    #pragma unroll
    for (int ct = 0; ct < 8; ++ct){
      bf16x8 bo = __builtin_bit_cast(bf16x8,
          *(const u16x8*)(bp + (ct * 16 + fr) * 32 + fq * 8));
      acc[ct] = __builtin_amdgcn_mfma_f32_16x16x32_bf16(a, bo, acc[ct], 0, 0, 0);
    }
    __syncthreads();
    b ^= 1;
  }

  float* op = out + (size_t)d * 6272;
  if (atom){
    #pragma unroll
    for (int ct = 0; ct < 8; ++ct){
      int c = ct * 16 + fr;
      #pragma unroll
      for (int r = 0; r < 4; ++r){
        int j = w * 16 + fq * 4 + r;
        if (j < 49) atomicAdd(op + j * 128 + c, acc[ct][r]);
      }
    }
  } else {
    #pragma unroll
    for (int ct = 0; ct < 8; ++ct){
      int c = ct * 16 + fr;
      #pragma unroll
      for (int r = 0; r < 4; ++r){
        int j = w * 16 + fq * 4 + r;
        if (j < 49) op[j * 128 + c] = acc[ct][r];
      }
    }
  }
}

// ---------------------------------------------------------------------------
extern "C" void kernel_launch(void* const* d_in, const int* in_sizes, int n_in,
                              void* d_out, int out_size, void* d_ws, size_t ws_size,
                              hipStream_t stream)
{
  (void)in_sizes; (void)n_in;
  const float* x       = (const float*)d_in[0];
  const float* x_edge  = (const float*)d_in[1];
  const int*   eidx    = (const int*)d_in[3];
  const float* wig     = (const float*)d_in[4];
  const float* wig_inv = (const float*)d_in[5];
  const float* env     = (const float*)d_in[6];
  const float* rad_w0  = (const float*)d_in[7];
  const float* rad_b0  = (const float*)d_in[8];
  const float* ln0_s   = (const float*)d_in[9];
  const float* ln0_b   = (const float*)d_in[10];
  const float* rad_w1  = (const float*)d_in[11];
  const float* rad_b1  = (const float*)d_in[12];
  const float* ln1_s   = (const float*)d_in[13];
  const float* ln1_b   = (const float*)d_in[14];
  const float* rad_w2  = (const float*)d_in[15];
  const float* rad_b2  = (const float*)d_in[16];
  const float* c1w0    = (const float*)d_in[17];
  const float* c1b0    = (const float*)d_in[18];
  const float* c1w1    = (const float*)d_in[19];
  const float* c1w2    = (const float*)d_in[20];
  const float* c2w0    = (const float*)d_in[21];
  const float* c2b0    = (const float*)d_in[22];
  const float* c2w1    = (const float*)d_in[23];
  const float* c2w2    = (const float*)d_in[24];
  float* out = (float*)d_out;

  char* base = (char*)d_ws;
  size_t off = 0;
  auto alloc = [&](size_t bytes) -> char* {
    off = (off + 255) & ~(size_t)255;
    char* r = base + off;
    off += bytes;
    return r;
  };

  // ---- fixed area: bf16 weights + xT + sort arrays ----
  u16* wtR0  = (u16*)alloc((size_t)256  * 128  * 2);
  u16* wtR1  = (u16*)alloc((size_t)256  * 256  * 2);
  u16* wtR2  = (u16*)alloc((size_t)4608 * 256  * 2);
  u16* wtC10 = (u16*)alloc((size_t)1792 * 1792 * 2);   // padded rows 1664..1791
  u16* wtC11 = (u16*)alloc((size_t)1536 * 1536 * 2);
  u16* wtC12 = (u16*)alloc((size_t)1280 * 1280 * 2);
  u16* wtC20 = (u16*)alloc((size_t)1024 * 896  * 2);   // padded rows 896..1023
  u16* wtC21 = (u16*)alloc((size_t)1536 * 768  * 2);
  u16* wtC22 = (u16*)alloc((size_t)1280 * 640  * 2);
  u16* xT    = (u16*)alloc((size_t)NN * 8192 * 2);
  int* cnt   = (int*)alloc(NN * 4);
  int* soff  = (int*)alloc(NN * 4);
  int* perm  = (int*)alloc(E_NUM * 4);

  // ---- chunk size ----
  size_t fixed_end = (off + 65536) & ~(size_t)65535;
  size_t avail = (ws_size > fixed_end + (1u << 20)) ? (ws_size - fixed_end - (1u << 20)) : 0;
  long CH0 = (long)(avail / 40960);
  if (CH0 > E_NUM) CH0 = E_NUM;
  if (CH0 < 64) CH0 = 64;
  int nch = (int)((E_NUM + CH0 - 1) / CH0);
  int CH = (E_NUM + nch - 1) / nch;
  if (CH > CH0) CH = (int)CH0;

  off = fixed_end;
  const size_t C = (size_t)CH;
  u16*   xe   = (u16*)alloc(C * 128 * 2);
  u16*   h0   = (u16*)alloc(C * 256 * 2);
  u16*   h1   = (u16*)alloc(C * 256 * 2);
  u16* region1 = (u16*)alloc(C * 4608 * 2);   // xrad -> msg2
  u16* region2 = (u16*)alloc(C * 7424 * 2);   // msgS -> conv2 outs
  u16* region3 = (u16*)alloc(C * 7424 * 2);   // conv1 outs -> msg3T
  u16* xrad = region1;
  u16* msg2 = region1;
  u16* msgS = region2;
  u16* m3x0 = region2;                 // (C,1024) padded
  u16* z10  = region2 + C * 1024;      // (C,1536)
  u16* z11  = region2 + C * 2560;      // (C,1536)
  u16* z20  = region2 + C * 4096;      // (C,1280)
  u16* z21  = region2 + C * 5376;      // (C,1280)
  u16* c1m0b = region3;                // (C,1792) padded
  u16* y10   = region3 + C * 1792;     // (C,1536)
  u16* y11   = region3 + C * 3328;     // (C,1536)
  u16* y20   = region3 + C * 4864;     // (C,1280)
  u16* y21   = region3 + C * 6144;     // (C,1280)
  u16* msg3T = region3;                // (C,4096) transposed (c,m)

  hipMemsetAsync(d_out, 0, (size_t)out_size * sizeof(float), stream);
  hipMemsetAsync(cnt, 0, NN * 4, stream);
  // zero only the pad rows of the padded weight buffers
  k_zero16<<<512, 256, 0, stream>>>(wtC10 + (size_t)1664 * 1792, 128 * 1792);
  k_zero16<<<512, 256, 0, stream>>>(wtC20 + (size_t)896 * 896, 128 * 896);

  // dst counting sort -> perm ; x transpose
  k_hist<<<(E_NUM + 255) / 256, 256, 0, stream>>>(eidx, cnt);
  k_scan<<<1, 256, 0, stream>>>(cnt, soff);
  k_scatter<<<(E_NUM + 255) / 256, 256, 0, stream>>>(eidx, soff, perm);
  k_xpose<<<NN, 256, 0, stream>>>(x, xT);

  // all 9 weight transposes in ONE launch
  {
    TW9 g;
    int b = 0;
    auto mk = [&](const float* in, u16* o, int K, int N) -> TW {
      TW t{in, o, K, N, b};
      b += (N >> 5) * (K >> 5);
      return t;
    };
    g.t[0] = mk(rad_w0, wtR0, 128, 256);
    g.t[1] = mk(rad_w1, wtR1, 256, 256);
    g.t[2] = mk(rad_w2, wtR2, 256, 4608);
    g.t[3] = mk(c1w0, wtC10, 1792, 1664);   // pad rows stay zero
    g.t[4] = mk(c1w1, wtC11, 1536, 1536);
    g.t[5] = mk(c1w2, wtC12, 1280, 1280);
    g.t[6] = mk(c2w0, wtC20, 896, 896);     // pad rows stay zero
    g.t[7] = mk(c2w1, wtC21, 768, 1536);
    g.t[8] = mk(c2w2, wtC22, 640, 1280);
    k_transpose_all<<<b, 256, 0, stream>>>(g);
  }

  for (int e0 = 0; e0 < E_NUM; e0 += CH){
    int cm = E_NUM - e0 < CH ? E_NUM - e0 : CH;
    int mb = (cm + 127) / 128;

    k_gather_xe<<<cm, 128, 0, stream>>>(x_edge, perm, xe, e0);

    // radial MLP
    k_gemm_ln<<<mb, 512, 0, stream>>>(xe, 128, wtR0, rad_b0, ln0_s, ln0_b, h0, cm, 128);
    k_gemm_ln<<<mb, 512, 0, stream>>>(h0, 256, wtR1, rad_b1, ln1_s, ln1_b, h1, cm, 256);
    k_gemm_bt256<<<dim3(4608 / 256, mb), 512, 0, stream>>>(
        h1, 256, wtR2, rad_b2, 4608, nullptr, xrad, 4608, cm, 256);

    // wigner forward
    k_wig_fwd<<<cm, 256, 0, stream>>>(xT, eidx, wig, xrad, msgS, perm, e0);

    // conv1: one segmented launch (all N % 256 == 0)
    {
      Seg5 g;
      int b = 0;
      auto mk = [&](const u16* A, const u16* B, u16* Cb, const float* bias,
                    int N, int K, int Nb) -> Seg {
        Seg s{A, B, Cb, bias, cm, N, K, 7424, b, Nb};
        b += (N >> 8) * mb;
        return s;
      };
      g.s[0] = mk(msgS,        wtC10, c1m0b, c1b0,   1792, 1792, 1664);
      g.s[1] = mk(msgS + 1792, wtC11, y10,   nullptr, 1536, 1536, 0);
      g.s[2] = mk(msgS + 3328, wtC11, y11,   nullptr, 1536, 1536, 0);
      g.s[3] = mk(msgS + 4864, wtC12, y20,   nullptr, 1280, 1280, 0);
      g.s[4] = mk(msgS + 6144, wtC12, y21,   nullptr, 1280, 1280, 0);
      g.nwg = b;
      k_gemm_seg<<<b, 512, 0, stream>>>(g);
    }

    k_gate<<<cm, 256, 0, stream>>>(c1m0b, y10, y11, y20, y21, msg2);

    // conv2: one segmented launch
    {
      Seg5 g;
      int b = 0;
      auto mk = [&](const u16* A, const u16* B, u16* Cb, const float* bias,
                    int N, int K, int Nb) -> Seg {
        Seg s{A, B, Cb, bias, cm, N, K, 3712, b, Nb};
        b += (N >> 8) * mb;
        return s;
      };
      g.s[0] = mk(msg2,        wtC20, m3x0, c2b0,   1024, 896, 896);
      g.s[1] = mk(msg2 + 896,  wtC21, z10,  nullptr, 1536, 768, 0);
      g.s[2] = mk(msg2 + 1664, wtC21, z11,  nullptr, 1536, 768, 0);
      g.s[3] = mk(msg2 + 2432, wtC22, z20,  nullptr, 1280, 640, 0);
      g.s[4] = mk(msg2 + 3072, wtC22, z21,  nullptr, 1280, 640, 0);
      g.nwg = b;
      k_gemm_seg<<<b, 512, 0, stream>>>(g);
    }

    k_recomb2<<<cm, 128, 0, stream>>>(m3x0, z10, z11, z20, z21, env, msg3T, perm, e0);

    // wigner inverse: node-indexed run-gather, W dbuf
    k_wig_inv<<<NN, 256, 0, stream>>>(msg3T, wig_inv, cnt, soff, out, perm, e0, cm);
  }
}